// Round 4
// baseline (292.984 us; speedup 1.0000x reference)
//
#include <hip/hip_runtime.h>

// B=4, S=2048, D=512, fp32 in/out. threshold 1.45e-1.
// Pipeline (Hermitian-packed D-FFTs: one 512-pt FFT serves TWO rows):
//  k1 : u=dyt_a(x); XfH = FFT_D(u)          (wave-register FFT, bitrev bins, half2 storage)
//  k2 : per column-PAIR: in-place radix-4 2048-pt S-FFT (fp32 LDS, fp16 global),
//       spectral op, exact inverse, *rtw/S. Twiddles from a 682-entry LDS table.
//  k3 : per ROW-PAIR: Hermitian combine, x1, dyt_b; q,k Parseval-packed in the
//       frequency domain (no inverse FFTs); v packed inverse FFT.
//  g1 : scores = q@k^T
//  smtr: full softmax per row written in place as bf16 P + v->vT transpose.
//  g2 : attn = P@vT, split-K x2, fp16 partials.
//  k5 : row-pair packed dyt_f + spectral filter (sums the two fp16 attn partials)
// R21: (a) wfft512 cross-lane stages now shuffle PACKED fp16 complex (one b32
// __shfl_xor moves re+im together) -- halves the DS-pipe ops per FFT (96->48).
// k3 counters (R20): 63us, VALUBusy 25%, HBM 12%, occupancy grid-capped at 16
// waves/CU -> bpermute-latency/LDS-pipe bound. Butterfly math stays fp32; only
// the exchanged value is fp16-rounded (err << existing bf16 output rounding).
// (b) gemm_bt reverted to R19 single-buffer 2-barrier loop: R20's 64KB dbuf
// halved gemm residency (4->2 blocks/CU) and was net-neutral-negative.

typedef __attribute__((ext_vector_type(8))) __bf16 bf16x8;
typedef __attribute__((ext_vector_type(4))) float floatx4;
typedef __attribute__((ext_vector_type(8))) _Float16 halfx8;
typedef __attribute__((ext_vector_type(8))) unsigned short ushortx8;
typedef __attribute__((ext_vector_type(2))) _Float16 half2v;   // 4B packed complex (re,im)
typedef __attribute__((ext_vector_type(4))) _Float16 half4v;   // 8B = two packed complex

__device__ __forceinline__ unsigned short f2bf(float x) {
    unsigned u = __float_as_uint(x);
    u = (u + 0x7fffu + ((u >> 16) & 1u)) >> 16;
    return (unsigned short)u;
}

__device__ __forceinline__ float dyt_tanh(float x) {
    float e = __expf(2.0f * x);
    return 1.0f - 2.0f / (e + 1.0f);
}

__device__ __forceinline__ void async_load16(const unsigned short* g, unsigned short* l) {
    __builtin_amdgcn_global_load_lds(
        (const __attribute__((address_space(1))) unsigned int*)g,
        (__attribute__((address_space(3))) unsigned int*)l, 16, 0, 0);
}

// pack/unpack complex fp32 <-> fp16x2 in one 32-bit reg (for packed shuffles)
__device__ __forceinline__ unsigned cpack(float r, float i) {
    union { half2v h2; unsigned u; } cv;
    cv.h2.x = (_Float16)r; cv.h2.y = (_Float16)i;
    return cv.u;
}
__device__ __forceinline__ float2 cunpack(unsigned u) {
    union { unsigned u; half2v h2; } cv; cv.u = u;
    return make_float2((float)cv.h2.x, (float)cv.h2.y);
}

// ---------- wave-level 512-pt FFT (8 pts/lane) ----------
__device__ __forceinline__ void wtw512(float (&tc)[12], float (&ts)[12], int lane) {
    const float w = -6.28318530717958647692f / 512.0f;
#pragma unroll
    for (int j = 0; j < 4; j++) __sincosf(w * (float)(j * 64 + lane), &ts[j], &tc[j]);
#pragma unroll
    for (int j = 0; j < 2; j++) __sincosf(w * (float)(2 * (j * 64 + lane)), &ts[4 + j], &tc[4 + j]);
    __sincosf(w * (float)(4 * lane), &ts[6], &tc[6]);
    __sincosf(w * (float)(8 * (lane & 31)), &ts[7], &tc[7]);
    __sincosf(w * (float)(16 * (lane & 15)), &ts[8], &tc[8]);
    __sincosf(w * (float)(32 * (lane & 7)), &ts[9], &tc[9]);
    __sincosf(w * (float)(64 * (lane & 3)), &ts[10], &tc[10]);
    __sincosf(w * (float)(128 * (lane & 1)), &ts[11], &tc[11]);
}

template <bool INV>
__device__ __forceinline__ void wfft512(float (&re)[8], float (&im)[8],
                                        const float (&tc)[12], const float (&ts)[12], int lane) {
    if (!INV) {
#pragma unroll
        for (int j = 0; j < 4; j++) {
            float ur = re[j], ui = im[j], vr = re[j + 4], vi = im[j + 4];
            re[j] = ur + vr; im[j] = ui + vi;
            float dr = ur - vr, di = ui - vi;
            re[j + 4] = dr * tc[j] - di * ts[j];
            im[j + 4] = dr * ts[j] + di * tc[j];
        }
#pragma unroll
        for (int g = 0; g < 8; g += 4)
#pragma unroll
            for (int jj = 0; jj < 2; jj++) {
                int j = g + jj;
                float ur = re[j], ui = im[j], vr = re[j + 2], vi = im[j + 2];
                re[j] = ur + vr; im[j] = ui + vi;
                float dr = ur - vr, di = ui - vi;
                re[j + 2] = dr * tc[4 + jj] - di * ts[4 + jj];
                im[j + 2] = dr * ts[4 + jj] + di * tc[4 + jj];
            }
#pragma unroll
        for (int j = 0; j < 8; j += 2) {
            float ur = re[j], ui = im[j], vr = re[j + 1], vi = im[j + 1];
            re[j] = ur + vr; im[j] = ui + vi;
            float dr = ur - vr, di = ui - vi;
            re[j + 1] = dr * tc[6] - di * ts[6];
            im[j + 1] = dr * ts[6] + di * tc[6];
        }
        // six cross-lane stages: packed fp16 complex shuffles (R21)
        unsigned pk[8];
#pragma unroll
        for (int j = 0; j < 8; j++) pk[j] = cpack(re[j], im[j]);
#pragma unroll
        for (int st = 0; st < 6; st++) {
            int h = 32 >> st;
            bool hi = (lane & h) != 0;
            float c = (st < 5) ? tc[7 + st] : 1.0f;
            float s = (st < 5) ? ts[7 + st] : 0.0f;
#pragma unroll
            for (int j = 0; j < 8; j++) {
                unsigned o = (unsigned)__shfl_xor((int)pk[j], h, 64);
                float2 ov = cunpack(o);
                float dr = ov.x - re[j], di = ov.y - im[j];
                float sr = re[j] + ov.x, si = im[j] + ov.y;
                re[j] = hi ? (dr * c - di * s) : sr;
                im[j] = hi ? (dr * s + di * c) : si;
                if (st < 5) pk[j] = cpack(re[j], im[j]);
            }
        }
    } else {
        // six cross-lane stages first (reverse order), packed shuffles
#pragma unroll
        for (int st = 5; st >= 0; st--) {
            int h = 32 >> st;
            bool hi = (lane & h) != 0;
            float c = (st < 5) ? tc[7 + st] : 1.0f;
            float s = (st < 5) ? ts[7 + st] : 0.0f;
#pragma unroll
            for (int j = 0; j < 8; j++) {
                float zr = re[j], zi = im[j];
                float vr = zr * c + zi * s;
                float vi = zi * c - zr * s;
                float mr = hi ? vr : zr;
                float mi = hi ? vi : zi;
                unsigned o = (unsigned)__shfl_xor((int)cpack(mr, mi), h, 64);
                float2 ov = cunpack(o);
                re[j] = hi ? (ov.x - vr) : (zr + ov.x);
                im[j] = hi ? (ov.y - vi) : (zi + ov.y);
            }
        }
#pragma unroll
        for (int j = 0; j < 8; j += 2) {
            float vr = re[j + 1] * tc[6] + im[j + 1] * ts[6];
            float vi = im[j + 1] * tc[6] - re[j + 1] * ts[6];
            re[j + 1] = re[j] - vr; im[j + 1] = im[j] - vi;
            re[j] += vr; im[j] += vi;
        }
#pragma unroll
        for (int g = 0; g < 8; g += 4)
#pragma unroll
            for (int jj = 0; jj < 2; jj++) {
                int j = g + jj;
                float vr = re[j + 2] * tc[4 + jj] + im[j + 2] * ts[4 + jj];
                float vi = im[j + 2] * tc[4 + jj] - re[j + 2] * ts[4 + jj];
                re[j + 2] = re[j] - vr; im[j + 2] = im[j] - vi;
                re[j] += vr; im[j] += vi;
            }
#pragma unroll
        for (int j = 0; j < 4; j++) {
            float vr = re[j + 4] * tc[j] + im[j + 4] * ts[j];
            float vi = im[j + 4] * tc[j] - re[j + 4] * ts[j];
            re[j + 4] = re[j] - vr; im[j + 4] = im[j] - vi;
            re[j] += vr; im[j] += vi;
        }
    }
}

// ---------------- k1 : dyt_a + forward D-FFT (half2 output) ----------------
__global__ __launch_bounds__(256) void k1_dyt_fftd(
        const float* __restrict__ x,
        const float* __restrict__ alpha, const float* __restrict__ w, const float* __restrict__ bia,
        half2v* __restrict__ xf) {
    int tid = threadIdx.x, lane = tid & 63, wv = tid >> 6;
    size_t row = (size_t)blockIdx.x * 4 + wv;
    float tc[12], ts[12];
    wtw512(tc, ts, lane);
    float re[8], im[8];
    float a = alpha[0];
    const float* xr = x + row * 512;
#pragma unroll
    for (int j = 0; j < 8; j++) {
        int d = j * 64 + lane;
        re[j] = dyt_tanh(a * xr[d]) * w[d] + bia[d];
        im[j] = 0.f;
    }
    wfft512<false>(re, im, tc, ts, lane);
#pragma unroll
    for (int j = 0; j < 8; j++) {
        int d = j * 64 + lane;
        xf[row * 512 + d] = (half2v){(_Float16)re[j], (_Float16)im[j]};
    }
}

// ---------------- k2 : in-place radix-4 2048-pt S-FFT, 2 cols/block ----------------
__device__ __forceinline__ int pidx4(int i) { return i + (i >> 3); }

// Both fwd and inv read the SAME table entry (c,s) = sincos(-2*pi*pos/(4h));
// inv applies the conjugate internally (u = y*(c - i*s)).
__device__ __forceinline__ void r4_fwd(float4* X, int t, int h, const half2v* tw) {
    int pos = t & (h - 1);
    int i = ((t & ~(h - 1)) << 2) | pos;
    int i0 = pidx4(i), i1 = pidx4(i + h), i2 = pidx4(i + 2 * h), i3 = pidx4(i + 3 * h);
    float4 a0 = X[i0], a1 = X[i1], a2 = X[i2], a3 = X[i3];
    half2v wv = tw[pos];
    float c1 = (float)wv.x, s1 = (float)wv.y;
    float c2 = c1 * c1 - s1 * s1, s2 = 2.f * c1 * s1;
    float c3 = c2 * c1 - s2 * s1, s3 = s2 * c1 + c2 * s1;
    float4 o0, o1, o2, o3;
    {
        float t0r = a0.x + a2.x, t0i = a0.y + a2.y, t1r = a0.x - a2.x, t1i = a0.y - a2.y;
        float t2r = a1.x + a3.x, t2i = a1.y + a3.y, t3r = a1.x - a3.x, t3i = a1.y - a3.y;
        o0.x = t0r + t2r; o0.y = t0i + t2i;
        float b1r = t1r + t3i, b1i = t1i - t3r;
        float b2r = t0r - t2r, b2i = t0i - t2i;
        float b3r = t1r - t3i, b3i = t1i + t3r;
        o1.x = b1r * c1 - b1i * s1; o1.y = b1r * s1 + b1i * c1;
        o2.x = b2r * c2 - b2i * s2; o2.y = b2r * s2 + b2i * c2;
        o3.x = b3r * c3 - b3i * s3; o3.y = b3r * s3 + b3i * c3;
    }
    {
        float t0r = a0.z + a2.z, t0i = a0.w + a2.w, t1r = a0.z - a2.z, t1i = a0.w - a2.w;
        float t2r = a1.z + a3.z, t2i = a1.w + a3.w, t3r = a1.z - a3.z, t3i = a1.w - a3.w;
        o0.z = t0r + t2r; o0.w = t0i + t2i;
        float b1r = t1r + t3i, b1i = t1i - t3r;
        float b2r = t0r - t2r, b2i = t0i - t2i;
        float b3r = t1r - t3i, b3i = t1i + t3r;
        o1.z = b1r * c1 - b1i * s1; o1.w = b1r * s1 + b1i * c1;
        o2.z = b2r * c2 - b2i * s2; o2.w = b2r * s2 + b2i * c2;
        o3.z = b3r * c3 - b3i * s3; o3.w = b3r * s3 + b3i * c3;
    }
    X[i0] = o0; X[i1] = o1; X[i2] = o2; X[i3] = o3;
}

__device__ __forceinline__ void r4_inv(float4* X, int t, int h, const half2v* tw) {
    int pos = t & (h - 1);
    int i = ((t & ~(h - 1)) << 2) | pos;
    int i0 = pidx4(i), i1 = pidx4(i + h), i2 = pidx4(i + 2 * h), i3 = pidx4(i + 3 * h);
    float4 y0 = X[i0], y1 = X[i1], y2 = X[i2], y3 = X[i3];
    half2v wv = tw[pos];
    float c1 = (float)wv.x, s1 = (float)wv.y;
    float c2 = c1 * c1 - s1 * s1, s2 = 2.f * c1 * s1;
    float c3 = c2 * c1 - s2 * s1, s3 = s2 * c1 + c2 * s1;
    float4 o0, o1, o2, o3;
    {
        float u1r = y1.x * c1 + y1.y * s1, u1i = y1.y * c1 - y1.x * s1;
        float u2r = y2.x * c2 + y2.y * s2, u2i = y2.y * c2 - y2.x * s2;
        float u3r = y3.x * c3 + y3.y * s3, u3i = y3.y * c3 - y3.x * s3;
        float s0r = y0.x + u2r, s0i = y0.y + u2i;
        float s1r = y0.x - u2r, s1i = y0.y - u2i;
        float s2r = u1r + u3r, s2i = u1i + u3i;
        float s3r = u1r - u3r, s3i = u1i - u3i;
        o0.x = s0r + s2r; o0.y = s0i + s2i;
        o2.x = s0r - s2r; o2.y = s0i - s2i;
        o1.x = s1r - s3i; o1.y = s1i + s3r;
        o3.x = s1r + s3i; o3.y = s1i - s3r;
    }
    {
        float u1r = y1.z * c1 + y1.w * s1, u1i = y1.w * c1 - y1.z * s1;
        float u2r = y2.z * c2 + y2.w * s2, u2i = y2.w * c2 - y2.z * s2;
        float u3r = y3.z * c3 + y3.w * s3, u3i = y3.w * c3 - y3.z * s3;
        float s0r = y0.z + u2r, s0i = y0.w + u2i;
        float s1r = y0.z - u2r, s1i = y0.w - u2i;
        float s2r = u1r + u3r, s2i = u1i + u3i;
        float s3r = u1r - u3r, s3i = u1i - u3i;
        o0.z = s0r + s2r; o0.w = s0i + s2i;
        o2.z = s0r - s2r; o2.w = s0i - s2i;
        o1.z = s1r - s3i; o1.w = s1i + s3r;
        o3.z = s1r + s3i; o3.w = s1i - s3r;
    }
    X[i0] = o0; X[i1] = o1; X[i2] = o2; X[i3] = o3;
}

__global__ __launch_bounds__(512) void k2_sfft(
        half2v* __restrict__ xf,
        const float* __restrict__ qr, const float* __restrict__ qi,
        const float* __restrict__ kr, const float* __restrict__ ki,
        const float* __restrict__ vr, const float* __restrict__ vi,
        const float* __restrict__ rtr, const float* __restrict__ rti) {
    __shared__ float4 buf[2304];
    __shared__ half2v twd[682];   // fwd twiddles: h=512@0, 128@512, 32@640, 8@672, 2@680
    int t = threadIdx.x;
    int g = blockIdx.x;
    int xcd = g & 7, r = g >> 3;
    int pp = xcd * 32 + (r & 31);
    int b = r >> 5;
    int p0 = pp * 2;
    half4v* colh = (half4v*)(xf + (size_t)b * 2048 * 512 + p0);

    // cooperative twiddle-table fill (2 passes over 512 threads)
    for (int i = t; i < 682; i += 512) {
        int h, off;
        if (i < 512)      { h = 512; off = 0; }
        else if (i < 640) { h = 128; off = 512; }
        else if (i < 672) { h = 32;  off = 640; }
        else if (i < 680) { h = 8;   off = 672; }
        else              { h = 2;   off = 680; }
        int pos = i - off;
        float s, c;
        __sincosf(-6.28318530717958647692f * (float)pos / (float)(4 * h), &s, &c);
        twd[i] = (half2v){(_Float16)c, (_Float16)s};
    }

#pragma unroll
    for (int c = 0; c < 4; c++) {
        int s = t + 512 * c;
        half4v h = colh[(size_t)s * 256];
        buf[pidx4(s)] = make_float4((float)h.x, (float)h.y, (float)h.z, (float)h.w);
    }
    __syncthreads(); r4_fwd(buf, t, 512, twd);
    __syncthreads(); r4_fwd(buf, t, 128, twd + 512);
    __syncthreads(); r4_fwd(buf, t, 32, twd + 640);
    __syncthreads(); r4_fwd(buf, t, 8, twd + 672);
    __syncthreads(); r4_fwd(buf, t, 2, twd + 680);
    __syncthreads();
#pragma unroll
    for (int c = 0; c < 2; c++) {
        int pr = t + 512 * c;
        int ia = pidx4(2 * pr), ib = pidx4(2 * pr + 1);
        float4 a = buf[ia], bb = buf[ib];
        buf[ia] = make_float4(a.x + bb.x, a.y + bb.y, a.z + bb.z, a.w + bb.w);
        buf[ib] = make_float4(a.x - bb.x, a.y - bb.y, a.z - bb.z, a.w - bb.w);
    }
    __syncthreads();

    int f0 = __brev((unsigned)p0) >> 23;
    int f1 = __brev((unsigned)(p0 + 1)) >> 23;
    float qw0r = qr[f0], qw0i = qi[f0], kw0r = kr[f0], kw0i = ki[f0], vw0r = vr[f0], vw0i = vi[f0];
    float qw1r = qr[f1], qw1i = qi[f1], kw1r = kr[f1], kw1i = ki[f1], vw1r = vr[f1], vw1i = vi[f1];
#pragma unroll
    for (int c = 0; c < 4; c++) {
        int idx = pidx4(t + 512 * c);
        float4 y = buf[idx];
        {
            float yr = y.x, yi = y.y;
            float qre = yr * qw0r - yi * qw0i, qim = yr * qw0i + yi * qw0r;
            float kre = yr * kw0r - yi * kw0i + 1e-12f, kim = yr * kw0i + yi * kw0r;
            float vre = yr * vw0r - yi * vw0i, vim = yr * vw0i + yi * vw0r;
            float inv = 1.0f / (kre * kre + kim * kim);
            float dre = (qre * kre + qim * kim) * inv;
            float dim = (qim * kre - qre * kim) * inv;
            y.x = dre * vre - dim * vim;
            y.y = dre * vim + dim * vre;
        }
        {
            float yr = y.z, yi = y.w;
            float qre = yr * qw1r - yi * qw1i, qim = yr * qw1i + yi * qw1r;
            float kre = yr * kw1r - yi * kw1i + 1e-12f, kim = yr * kw1i + yi * kw1r;
            float vre = yr * vw1r - yi * vw1i, vim = yr * vw1i + yi * vw1r;
            float inv = 1.0f / (kre * kre + kim * kim);
            float dre = (qre * kre + qim * kim) * inv;
            float dim = (qim * kre - qre * kim) * inv;
            y.z = dre * vre - dim * vim;
            y.w = dre * vim + dim * vre;
        }
        buf[idx] = y;
    }

    __syncthreads();
#pragma unroll
    for (int c = 0; c < 2; c++) {
        int pr = t + 512 * c;
        int ia = pidx4(2 * pr), ib = pidx4(2 * pr + 1);
        float4 a = buf[ia], bb = buf[ib];
        buf[ia] = make_float4(a.x + bb.x, a.y + bb.y, a.z + bb.z, a.w + bb.w);
        buf[ib] = make_float4(a.x - bb.x, a.y - bb.y, a.z - bb.z, a.w - bb.w);
    }
    __syncthreads(); r4_inv(buf, t, 2, twd + 680);
    __syncthreads(); r4_inv(buf, t, 8, twd + 672);
    __syncthreads(); r4_inv(buf, t, 32, twd + 640);
    __syncthreads(); r4_inv(buf, t, 128, twd + 512);
    __syncthreads(); r4_inv(buf, t, 512, twd);
    __syncthreads();

    const float sc = 1.0f / 2048.0f;
    float r0r = rtr[f0] * sc, r0i = rti[f0] * sc;
    float r1r = rtr[f1] * sc, r1i = rti[f1] * sc;
#pragma unroll
    for (int c = 0; c < 4; c++) {
        int s = t + 512 * c;
        float4 z = buf[pidx4(s)];
        float ox = z.x * r0r - z.y * r0i, oy = z.x * r0i + z.y * r0r;
        float oz = z.z * r1r - z.w * r1i, ow = z.z * r1i + z.w * r1r;
        colh[(size_t)s * 256] = (half4v){(_Float16)ox, (_Float16)oy, (_Float16)oz, (_Float16)ow};
    }
}

// ---------------- k3 : row-pair residual + dyt_b + q/k (Parseval-packed) + v ----------------
__global__ __launch_bounds__(256) void k3_mid(
        const half2v* __restrict__ xf,
        const float* __restrict__ x,
        const float* __restrict__ alpha, const float* __restrict__ w, const float* __restrict__ bia,
        const float* __restrict__ qr, const float* __restrict__ qi,
        const float* __restrict__ kr, const float* __restrict__ ki,
        const float* __restrict__ vr, const float* __restrict__ vi,
        float* __restrict__ x1,
        unsigned short* __restrict__ qb, unsigned short* __restrict__ kb, unsigned short* __restrict__ vb) {
    __shared__ __align__(16) char smem[4 * 1024 * 8];  // 32KB
    int tid = threadIdx.x, lane = tid & 63, wv = tid >> 6;
    float2* zb = (float2*)(smem + wv * 8192);          // phase1: wave-private 8KB
    float* wbs = (float*)smem;                          // [6][512]=12KB (after combine)
    float2* zf = (float2*)(smem + 12288 + wv * 4096);  // phase2: wave-private 4KB
    size_t pr = (size_t)blockIdx.x * 4 + wv;
    size_t r1 = pr * 2, r2 = r1 + 1;
    float tc[12], ts[12];
    wtw512(tc, ts, lane);

    float xa[8], xb2[8];
#pragma unroll
    for (int j = 0; j < 8; j++) {
        int d = j * 64 + lane;
        half2v h1 = xf[r1 * 512 + d];
        half2v h2 = xf[r2 * 512 + d];
        zb[d]       = make_float2((float)h1.x, (float)h1.y);
        zb[512 + d] = make_float2((float)h2.x, (float)h2.y);
        xa[j]  = x[r1 * 512 + d];
        xb2[j] = x[r2 * 512 + d];
    }
    float re[8], im[8];
#pragma unroll
    for (int j = 0; j < 8; j++) {
        int d = j * 64 + lane;
        int fd = __brev((unsigned)d) >> 23;
        int dp = __brev((unsigned)((512 - fd) & 511)) >> 23;
        float2 z1 = zb[d], z1p = zb[dp];
        float2 z2 = zb[512 + d], z2p = zb[512 + dp];
        float h1r = 0.5f * (z1.x + z1p.x), h1i = 0.5f * (z1.y - z1p.y);
        float h2r = 0.5f * (z2.x + z2p.x), h2i = 0.5f * (z2.y - z2p.y);
        re[j] = h1r - h2i;
        im[j] = h1i + h2r;
    }
    __syncthreads();
    for (int idx = tid; idx < 512; idx += 256) {
        int f = __brev((unsigned)idx) >> 23;
        int gg = (512 - f) & 511;
        float aa = (f == 0 || f == 256) ? 0.04419417382415922f : 0.0625f;
        float ah = aa * 0.5f;
        const float s5 = 0.5f * (1.0f / 512.0f);
        wbs[0 * 512 + idx] = ah * (qr[f] + qr[gg]); wbs[1 * 512 + idx] = ah * (qi[f] - qi[gg]);
        wbs[2 * 512 + idx] = ah * (kr[f] + kr[gg]); wbs[3 * 512 + idx] = ah * (ki[f] - ki[gg]);
        wbs[4 * 512 + idx] = s5 * (vr[f] + vr[gg]); wbs[5 * 512 + idx] = s5 * (vi[f] - vi[gg]);
    }

    wfft512<true>(re, im, tc, ts, lane);
    float a = alpha[0];
    float gre[8], gim[8];
#pragma unroll
    for (int j = 0; j < 8; j++) {
        int d = j * 64 + lane;
        float v1 = re[j] * (1.0f / 512.0f) + xa[j];
        float v2 = im[j] * (1.0f / 512.0f) + xb2[j];
        x1[r1 * 512 + d] = v1;
        x1[r2 * 512 + d] = v2;
        gre[j] = dyt_tanh(a * v1) * w[d] + bia[d];
        gim[j] = dyt_tanh(a * v2) * w[d] + bia[d];
    }
    wfft512<false>(gre, gim, tc, ts, lane);
    __syncthreads();

#pragma unroll
    for (int j = 0; j < 8; j++)
        zf[j * 64 + lane] = make_float2(gre[j], gim[j]);

    float pvr[8], pvi[8];
#pragma unroll
    for (int j = 0; j < 8; j++) {
        int i = j * 64 + lane;
        float wr0 = wbs[4 * 512 + i], wi0 = wbs[5 * 512 + i];
        pvr[j] = gre[j] * wr0 - gim[j] * wi0;
        pvi[j] = gre[j] * wi0 + gim[j] * wr0;
    }

    bool odd = (lane & 1) != 0;
#pragma unroll
    for (int j = 0; j < 8; j++) {
        int d = j * 64 + lane;
        int fd = __brev((unsigned)d) >> 23;
        int dp = __brev((unsigned)((512 - fd) & 511)) >> 23;
        float2 Zp = zf[dp];
        float zr = gre[j], zi = gim[j];
        float A1r = 0.5f * (zr + Zp.x), A1i = 0.5f * (zi - Zp.y);
        float A2r = 0.5f * (zi + Zp.y), A2i = 0.5f * (Zp.x - zr);
        float wr0 = wbs[0 * 512 + d], wi0 = wbs[1 * 512 + d];
        float Q1r = A1r * wr0 - A1i * wi0, Q1i = A1r * wi0 + A1i * wr0;
        float Q2r = A2r * wr0 - A2i * wi0, Q2i = A2r * wi0 + A2i * wr0;
        qb[r1 * 512 + d] = f2bf(odd ? -Q1i : Q1r);
        qb[r2 * 512 + d] = f2bf(odd ? -Q2i : Q2r);
        float wr1 = wbs[2 * 512 + d], wi1 = wbs[3 * 512 + d];
        float K1r = A1r * wr1 - A1i * wi1, K1i = A1r * wi1 + A1i * wr1;
        float K2r = A2r * wr1 - A2i * wi1, K2i = A2r * wi1 + A2i * wr1;
        kb[r1 * 512 + d] = f2bf(odd ? -K1i : K1r);
        kb[r2 * 512 + d] = f2bf(odd ? -K2i : K2r);
    }

    wfft512<true>(pvr, pvi, tc, ts, lane);
#pragma unroll
    for (int j = 0; j < 8; j++) {
        int d = j * 64 + lane;
        vb[r1 * 512 + d] = f2bf(pvr[j]);
        vb[r2 * 512 + d] = f2bf(pvi[j]);
    }
}

// ---------------- unified bt-GEMM (BK=64, global_load_lds, XOR-swizzled LDS) ----------------
// R21: reverted to R19 single-buffer 2-barrier loop (32KB LDS, 4 blocks/CU).
__global__ __launch_bounds__(256) void gemm_bt(
        const unsigned short* __restrict__ A, const unsigned short* __restrict__ Bt,
        void* __restrict__ C, int M, int N, int Ks, int kseg, float scale, int out_half) {
    int tilesM = M >> 7, tilesN = N >> 7;
    int perBatch = tilesM * tilesN;
    int l = blockIdx.x;
    int seg = blockIdx.y;
    int s = l & 7, t = l >> 3;
    int cnt = perBatch >> 3;
    int bz = t / cnt;
    int u = t - bz * cnt;
    int pn = tilesN >> 1, pm = tilesM >> 2;
    int n0 = ((s & 1) * pn + (u % pn)) << 7;
    int m0 = ((s >> 1) * pm + (u / pn)) << 7;
    int kbase = seg * kseg;

    const unsigned short* Ab = A + (size_t)bz * M * Ks;
    const unsigned short* Bb = Bt + (size_t)bz * N * Ks;
    __shared__ __align__(16) unsigned short smem[2 * 128 * 64];
    unsigned short* As = smem;
    unsigned short* Bs = smem + 128 * 64;
    int tid = threadIdx.x;
    int wave = tid >> 6, lane = tid & 63;
    int wm = (wave >> 1) * 64, wn = (wave & 1) * 64;
    int lrow = lane & 15, lq = lane >> 4;
    floatx4 acc[4][4];
#pragma unroll
    for (int i = 0; i < 4; i++)
#pragma unroll
        for (int j = 0; j < 4; j++)
            acc[i][j] = (floatx4){0.f, 0.f, 0.f, 0.f};

    int lr = lane >> 3;
    int lcs = lane & 7;
    for (int k0 = kbase; k0 < kbase + kseg; k0 += 64) {
        __syncthreads();
#pragma unroll
        for (int i = 0; i < 4; i++) {
            int c = wave * 4 + i;
            int r = c * 8 + lr;
            int gcol = ((lcs ^ (r & 7)) << 3);
            async_load16(Ab + (size_t)(m0 + r) * Ks + k0 + gcol, As + c * 512);
            async_load16(Bb + (size_t)(n0 + r) * Ks + k0 + gcol, Bs + c * 512);
        }
        __syncthreads();
        bf16x8 a0[4], a1[4], b0[4], b1[4];
#pragma unroll
        for (int mi = 0; mi < 4; mi++) {
            int r = wm + mi * 16 + lrow;
            a0[mi] = *(const bf16x8*)(As + r * 64 + ((lq ^ (r & 7)) << 3));
            a1[mi] = *(const bf16x8*)(As + r * 64 + (((lq + 4) ^ (r & 7)) << 3));
        }
#pragma unroll
        for (int ni = 0; ni < 4; ni++) {
            int r = wn + ni * 16 + lrow;
            b0[ni] = *(const bf16x8*)(Bs + r * 64 + ((lq ^ (r & 7)) << 3));
            b1[ni] = *(const bf16x8*)(Bs + r * 64 + (((lq + 4) ^ (r & 7)) << 3));
        }
#pragma unroll
        for (int mi = 0; mi < 4; mi++)
#pragma unroll
            for (int ni = 0; ni < 4; ni++) {
                acc[mi][ni] = __builtin_amdgcn_mfma_f32_16x16x32_bf16(a0[mi], b0[ni], acc[mi][ni], 0, 0, 0);
                acc[mi][ni] = __builtin_amdgcn_mfma_f32_16x16x32_bf16(a1[mi], b1[ni], acc[mi][ni], 0, 0, 0);
            }
    }
    size_t cbase = ((size_t)seg * 4 + bz) * (size_t)M * N;
    int lr0 = (wave >> 1) * 16 + lq * 4;
    for (int mi = 0; mi < 4; mi++) {
        __syncthreads();
        if (out_half) {
            _Float16* Cs = (_Float16*)smem;
            for (int ni = 0; ni < 4; ni++)
                for (int r = 0; r < 4; r++)
                    Cs[(lr0 + r) * 128 + wn + ni * 16 + lrow] = (_Float16)(acc[mi][ni][r] * scale);
            __syncthreads();
            for (int h = 0; h < 2; h++) {
                int chunk = tid + h * 256;
                int rl = chunk >> 4, cb = (chunk & 15) * 16;
                int grow = m0 + mi * 16 + (rl & 15) + (rl >> 4) * 64;
                *(uint4*)((char*)C + (cbase + (size_t)grow * N + n0) * 2 + cb) =
                    *(const uint4*)((const char*)Cs + rl * 256 + cb);
            }
        } else {
            float* Cs = (float*)smem;
            for (int ni = 0; ni < 4; ni++)
                for (int r = 0; r < 4; r++)
                    Cs[(lr0 + r) * 128 + wn + ni * 16 + lrow] = acc[mi][ni][r] * scale;
            __syncthreads();
            for (int h = 0; h < 4; h++) {
                int chunk = tid + h * 256;
                int rl = chunk >> 5, cb = (chunk & 31) * 16;
                int grow = m0 + mi * 16 + (rl & 15) + (rl >> 4) * 64;
                *(uint4*)((char*)C + (cbase + (size_t)grow * N + n0) * 4 + cb) =
                    *(const uint4*)((const char*)Cs + rl * 512 + cb);
            }
        }
    }
}

// ---------------- softmax (in-place bf16 P) + v->vT transpose, one grid ----------------
__global__ __launch_bounds__(256) void sm_tr(
        const _Float16* __restrict__ Sc, unsigned short* __restrict__ P,
        const unsigned short* __restrict__ vb, unsigned short* __restrict__ vT) {
    __shared__ __align__(16) char lds[64 * 65 * 2];  // transpose tile; softmax uses first 16B
    if (blockIdx.x < 8192) {
        float* red = (float*)lds;
        int tid = threadIdx.x;
        size_t row = blockIdx.x;
        halfx8 hv = *(const halfx8*)(Sc + row * 2048 + tid * 8);
        float v[8];
#pragma unroll
        for (int j = 0; j < 8; j++) v[j] = (float)hv[j];
        float mx = v[0];
#pragma unroll
        for (int j = 1; j < 8; j++) mx = fmaxf(mx, v[j]);
        for (int off = 32; off >= 1; off >>= 1) mx = fmaxf(mx, __shfl_xor(mx, off));
        int wv = tid >> 6;
        if ((tid & 63) == 0) red[wv] = mx;
        __syncthreads();
        mx = fmaxf(fmaxf(red[0], red[1]), fmaxf(red[2], red[3]));
        float e[8], sum = 0.f;
#pragma unroll
        for (int j = 0; j < 8; j++) { e[j] = __expf(v[j] - mx); sum += e[j]; }
        for (int off = 32; off >= 1; off >>= 1) sum += __shfl_xor(sum, off);
        __syncthreads();
        if ((tid & 63) == 0) red[wv] = sum;
        __syncthreads();
        float inv = 1.0f / (red[0] + red[1] + red[2] + red[3]);
        ushortx8 o;
#pragma unroll
        for (int j = 0; j < 8; j++) o[j] = f2bf(e[j] * inv);
        *(ushortx8*)(P + row * 2048 + tid * 8) = o;
    } else {
        unsigned short (*tile)[65] = (unsigned short (*)[65])lds;
        int id = blockIdx.x - 8192;           // 1024 transpose blocks: (32, 8, 4)
        int sx = id & 31, dy = (id >> 5) & 7, bz = id >> 8;
        int s0 = sx * 64, d0 = dy * 64;
        int tx = threadIdx.x & 63, ty = threadIdx.x >> 6;
        for (int j = 0; j < 16; j++) {
            int s = ty + j * 4;
            tile[s][tx] = vb[((size_t)bz * 2048 + s0 + s) * 512 + d0 + tx];
        }
        __syncthreads();
        for (int j = 0; j < 16; j++) {
            int d = ty + j * 4;
            vT[((size_t)bz * 512 + d0 + d) * 2048 + s0 + tx] = tile[tx][d];
        }
    }
}

// ---------------- k5 : row-pair residual + dyt_f + spectral filter ----------------
__global__ __launch_bounds__(256) void k5_ffn(
        const _Float16* __restrict__ attn0, const _Float16* __restrict__ attn1,
        const float* __restrict__ x1,
        const float* __restrict__ alpha, const float* __restrict__ w, const float* __restrict__ bia,
        const float* __restrict__ br, const float* __restrict__ bi,
        float* __restrict__ out) {
    __shared__ float wbs[2][512];
    int tid = threadIdx.x, lane = tid & 63, wv = tid >> 6;
    size_t pr = (size_t)blockIdx.x * 4 + wv;
    size_t r1 = pr * 2, r2 = r1 + 1;
    for (int idx = tid; idx < 512; idx += 256) {
        int f = __brev((unsigned)idx) >> 23;
        int gg = (512 - f) & 511;
        wbs[0][idx] = 0.5f * (br[f] + br[gg]) * (1.0f / 512.0f);
        wbs[1][idx] = 0.5f * (bi[f] - bi[gg]) * (1.0f / 512.0f);
    }
    float tc[12], ts[12];
    wtw512(tc, ts, lane);
    float a = alpha[0];
    float re[8], im[8], x2a[8], x2b[8];
#pragma unroll
    for (int j = 0; j < 8; j++) {
        int d = j * 64 + lane;
        float v1 = (float)attn0[r1 * 512 + d] + (float)attn1[r1 * 512 + d] + x1[r1 * 512 + d];
        float v2 = (float)attn0[r2 * 512 + d] + (float)attn1[r2 * 512 + d] + x1[r2 * 512 + d];
        x2a[j] = v1; x2b[j] = v2;
        re[j] = dyt_tanh(a * v1) * w[d] + bia[d];
        im[j] = dyt_tanh(a * v2) * w[d] + bia[d];
    }
    wfft512<false>(re, im, tc, ts, lane);
    __syncthreads();
#pragma unroll
    for (int j = 0; j < 8; j++) {
        int i = j * 64 + lane;
        float wr0 = wbs[0][i], wi0 = wbs[1][i];
        float rr = re[j], ii = im[j];
        re[j] = rr * wr0 - ii * wi0;
        im[j] = rr * wi0 + ii * wr0;
    }
    wfft512<true>(re, im, tc, ts, lane);
#pragma unroll
    for (int j = 0; j < 8; j++) {
        int d = j * 64 + lane;
        out[r1 * 512 + d] = re[j] + x2a[j];
        out[r2 * 512 + d] = im[j] + x2b[j];
    }
}

extern "C" void kernel_launch(void* const* d_in, const int* in_sizes, int n_in,
                              void* d_out, int out_size, void* d_ws, size_t ws_size,
                              hipStream_t stream) {
    const float* x      = (const float*)d_in[0];
    const float* a_qr   = (const float*)d_in[1];
    const float* a_kr   = (const float*)d_in[2];
    const float* a_vr   = (const float*)d_in[3];
    const float* a_rtr  = (const float*)d_in[4];
    const float* b_qr   = (const float*)d_in[5];
    const float* b_kr   = (const float*)d_in[6];
    const float* b_vr   = (const float*)d_in[7];
    /* f_ar = d_in[8] unused (dead gelu branch) */
    const float* f_br   = (const float*)d_in[9];
    const float* a_qi   = (const float*)d_in[10];
    const float* a_ki   = (const float*)d_in[11];
    const float* a_vi   = (const float*)d_in[12];
    const float* a_rti  = (const float*)d_in[13];
    const float* b_qi   = (const float*)d_in[14];
    const float* b_ki   = (const float*)d_in[15];
    const float* b_vi   = (const float*)d_in[16];
    /* f_ai = d_in[17] unused */
    const float* f_bi   = (const float*)d_in[18];
    /* f_bias = d_in[19] unused (dead gelu branch) */
    const float* dyta_alpha = (const float*)d_in[20];
    const float* dyta_w     = (const float*)d_in[21];
    const float* dyta_b     = (const float*)d_in[22];
    const float* dytb_alpha = (const float*)d_in[23];
    const float* dytb_w     = (const float*)d_in[24];
    const float* dytb_b     = (const float*)d_in[25];
    const float* dytf_alpha = (const float*)d_in[26];
    const float* dytf_w     = (const float*)d_in[27];
    const float* dytf_b     = (const float*)d_in[28];
    (void)in_sizes; (void)n_in; (void)out_size; (void)ws_size;

    char* ws = (char*)d_ws;
    const size_t MB = 1024 * 1024;
    half2v* xfH = (half2v*)(ws + 0 * MB);           // 16MB packed fp16 complex
    float* x1   = (float*)(ws + 32 * MB);           // 16MB
    unsigned short* qb = (unsigned short*)(ws + 48 * MB);  // 8MB
    unsigned short* kb = (unsigned short*)(ws + 56 * MB);  // 8MB
    unsigned short* vb = (unsigned short*)(ws + 64 * MB);  // 8MB
    unsigned short* vT = (unsigned short*)(ws + 72 * MB);  // 8MB
    _Float16* scores   = (_Float16*)(ws + 0 * MB);  // 32MB, overlays dead xfH
    unsigned short* Pb = (unsigned short*)(ws + 0 * MB);   // bf16 P, in place over scores
    _Float16* attnP    = (_Float16*)(ws + 81 * MB); // 16MB: two 8MB fp16 K-split partials
    float* outp = (float*)d_out;

    k1_dyt_fftd<<<2048, 256, 0, stream>>>(x, dyta_alpha, dyta_w, dyta_b, xfH);
    k2_sfft<<<1024, 512, 0, stream>>>(xfH, a_qr, a_qi, a_kr, a_ki, a_vr, a_vi, a_rtr, a_rti);
    k3_mid<<<1024, 256, 0, stream>>>(xfH, x, dytb_alpha, dytb_w, dytb_b,
                                     b_qr, b_qi, b_kr, b_ki, b_vr, b_vi, x1, qb, kb, vb);
    gemm_bt<<<1024, 256, 0, stream>>>(qb, kb, scores, 2048, 2048, 512, 512,
                                      0.04419417382415922f, 1);
    sm_tr<<<9216, 256, 0, stream>>>(scores, Pb, vb, vT);
    gemm_bt<<<dim3(256, 2), 256, 0, stream>>>(Pb, vT, attnP, 2048, 512, 2048, 1024,
                                              1.0f, 1);
    k5_ffn<<<1024, 256, 0, stream>>>(attnP, attnP + (size_t)4 * 2048 * 512, x1,
                                     dytf_alpha, dytf_w, dytf_b, f_br, f_bi, outp);
}

// Round 5
// 286.671 us; speedup vs baseline: 1.0220x; 1.0220x over previous
//
#include <hip/hip_runtime.h>

// B=4, S=2048, D=512, fp32 in/out. threshold 1.45e-1.
// Pipeline (Hermitian-packed D-FFTs: one 512-pt FFT serves TWO rows):
//  k1 : u=dyt_a(x); XfH = FFT_D(u)          (wave-register FFT, bitrev bins, half2 storage)
//  k2 : per column-PAIR: in-place radix-4 2048-pt S-FFT (fp32 LDS, fp16 global),
//       spectral op, exact inverse, *rtw/S. Twiddles from a 682-entry LDS table.
//  k3 : per ROW-PAIR: Hermitian combine, x1, dyt_b; q,k Parseval-packed in the
//       frequency domain (no inverse FFTs); v packed inverse FFT.
//  g1 : scores = q@k^T
//  smtr: full softmax per row written in place as bf16 P + v->vT transpose.
//  g2 : attn = P@vT, split-K x4 (R22: was x2 -> only 2 blocks/CU; x4 doubles
//       g2 residency to 4 blocks/CU matching g1), fp16 partials.
//  k5 : row-pair packed dyt_f + spectral filter (sums the FOUR fp16 partials)
// R22: wfft512 reverted to fp32 dual shuffles. R21's packed-fp16 shuffle HURT
// (k3 63->69.6us, VALUBusy 25->28.6%): the 4 v_cvt per exchange sat on the
// serial butterfly chain -- k3 is chain-LATENCY bound at 4 waves/SIMD (grid-
// structural: 4096 waves total), not DS-pipe-throughput bound. Do not re-add
// VALU work to the shuffle chain.

typedef __attribute__((ext_vector_type(8))) __bf16 bf16x8;
typedef __attribute__((ext_vector_type(4))) float floatx4;
typedef __attribute__((ext_vector_type(8))) _Float16 halfx8;
typedef __attribute__((ext_vector_type(8))) unsigned short ushortx8;
typedef __attribute__((ext_vector_type(2))) _Float16 half2v;   // 4B packed complex (re,im)
typedef __attribute__((ext_vector_type(4))) _Float16 half4v;   // 8B = two packed complex

__device__ __forceinline__ unsigned short f2bf(float x) {
    unsigned u = __float_as_uint(x);
    u = (u + 0x7fffu + ((u >> 16) & 1u)) >> 16;
    return (unsigned short)u;
}

__device__ __forceinline__ float dyt_tanh(float x) {
    float e = __expf(2.0f * x);
    return 1.0f - 2.0f / (e + 1.0f);
}

__device__ __forceinline__ void async_load16(const unsigned short* g, unsigned short* l) {
    __builtin_amdgcn_global_load_lds(
        (const __attribute__((address_space(1))) unsigned int*)g,
        (__attribute__((address_space(3))) unsigned int*)l, 16, 0, 0);
}

// ---------- wave-level 512-pt FFT (8 pts/lane) ----------
__device__ __forceinline__ void wtw512(float (&tc)[12], float (&ts)[12], int lane) {
    const float w = -6.28318530717958647692f / 512.0f;
#pragma unroll
    for (int j = 0; j < 4; j++) __sincosf(w * (float)(j * 64 + lane), &ts[j], &tc[j]);
#pragma unroll
    for (int j = 0; j < 2; j++) __sincosf(w * (float)(2 * (j * 64 + lane)), &ts[4 + j], &tc[4 + j]);
    __sincosf(w * (float)(4 * lane), &ts[6], &tc[6]);
    __sincosf(w * (float)(8 * (lane & 31)), &ts[7], &tc[7]);
    __sincosf(w * (float)(16 * (lane & 15)), &ts[8], &tc[8]);
    __sincosf(w * (float)(32 * (lane & 7)), &ts[9], &tc[9]);
    __sincosf(w * (float)(64 * (lane & 3)), &ts[10], &tc[10]);
    __sincosf(w * (float)(128 * (lane & 1)), &ts[11], &tc[11]);
}

template <bool INV>
__device__ __forceinline__ void wfft512(float (&re)[8], float (&im)[8],
                                        const float (&tc)[12], const float (&ts)[12], int lane) {
    if (!INV) {
#pragma unroll
        for (int j = 0; j < 4; j++) {
            float ur = re[j], ui = im[j], vr = re[j + 4], vi = im[j + 4];
            re[j] = ur + vr; im[j] = ui + vi;
            float dr = ur - vr, di = ui - vi;
            re[j + 4] = dr * tc[j] - di * ts[j];
            im[j + 4] = dr * ts[j] + di * tc[j];
        }
#pragma unroll
        for (int g = 0; g < 8; g += 4)
#pragma unroll
            for (int jj = 0; jj < 2; jj++) {
                int j = g + jj;
                float ur = re[j], ui = im[j], vr = re[j + 2], vi = im[j + 2];
                re[j] = ur + vr; im[j] = ui + vi;
                float dr = ur - vr, di = ui - vi;
                re[j + 2] = dr * tc[4 + jj] - di * ts[4 + jj];
                im[j + 2] = dr * ts[4 + jj] + di * tc[4 + jj];
            }
#pragma unroll
        for (int j = 0; j < 8; j += 2) {
            float ur = re[j], ui = im[j], vr = re[j + 1], vi = im[j + 1];
            re[j] = ur + vr; im[j] = ui + vi;
            float dr = ur - vr, di = ui - vi;
            re[j + 1] = dr * tc[6] - di * ts[6];
            im[j + 1] = dr * ts[6] + di * tc[6];
        }
#pragma unroll
        for (int st = 0; st < 6; st++) {
            int h = 32 >> st;
            bool hi = (lane & h) != 0;
            float c = (st < 5) ? tc[7 + st] : 1.0f;
            float s = (st < 5) ? ts[7 + st] : 0.0f;
#pragma unroll
            for (int j = 0; j < 8; j++) {
                float orr = __shfl_xor(re[j], h, 64);
                float oii = __shfl_xor(im[j], h, 64);
                float dr = orr - re[j], di = oii - im[j];
                float sr = re[j] + orr, si = im[j] + oii;
                re[j] = hi ? (dr * c - di * s) : sr;
                im[j] = hi ? (dr * s + di * c) : si;
            }
        }
    } else {
#pragma unroll
        for (int st = 5; st >= 0; st--) {
            int h = 32 >> st;
            bool hi = (lane & h) != 0;
            float c = (st < 5) ? tc[7 + st] : 1.0f;
            float s = (st < 5) ? ts[7 + st] : 0.0f;
#pragma unroll
            for (int j = 0; j < 8; j++) {
                float zr = re[j], zi = im[j];
                float vr = zr * c + zi * s;
                float vi = zi * c - zr * s;
                float mr = hi ? vr : zr;
                float mi = hi ? vi : zi;
                float orr = __shfl_xor(mr, h, 64);
                float oii = __shfl_xor(mi, h, 64);
                re[j] = hi ? (orr - vr) : (zr + orr);
                im[j] = hi ? (oii - vi) : (zi + oii);
            }
        }
#pragma unroll
        for (int j = 0; j < 8; j += 2) {
            float vr = re[j + 1] * tc[6] + im[j + 1] * ts[6];
            float vi = im[j + 1] * tc[6] - re[j + 1] * ts[6];
            re[j + 1] = re[j] - vr; im[j + 1] = im[j] - vi;
            re[j] += vr; im[j] += vi;
        }
#pragma unroll
        for (int g = 0; g < 8; g += 4)
#pragma unroll
            for (int jj = 0; jj < 2; jj++) {
                int j = g + jj;
                float vr = re[j + 2] * tc[4 + jj] + im[j + 2] * ts[4 + jj];
                float vi = im[j + 2] * tc[4 + jj] - re[j + 2] * ts[4 + jj];
                re[j + 2] = re[j] - vr; im[j + 2] = im[j] - vi;
                re[j] += vr; im[j] += vi;
            }
#pragma unroll
        for (int j = 0; j < 4; j++) {
            float vr = re[j + 4] * tc[j] + im[j + 4] * ts[j];
            float vi = im[j + 4] * tc[j] - re[j + 4] * ts[j];
            re[j + 4] = re[j] - vr; im[j + 4] = im[j] - vi;
            re[j] += vr; im[j] += vi;
        }
    }
}

// ---------------- k1 : dyt_a + forward D-FFT (half2 output) ----------------
__global__ __launch_bounds__(256) void k1_dyt_fftd(
        const float* __restrict__ x,
        const float* __restrict__ alpha, const float* __restrict__ w, const float* __restrict__ bia,
        half2v* __restrict__ xf) {
    int tid = threadIdx.x, lane = tid & 63, wv = tid >> 6;
    size_t row = (size_t)blockIdx.x * 4 + wv;
    float tc[12], ts[12];
    wtw512(tc, ts, lane);
    float re[8], im[8];
    float a = alpha[0];
    const float* xr = x + row * 512;
#pragma unroll
    for (int j = 0; j < 8; j++) {
        int d = j * 64 + lane;
        re[j] = dyt_tanh(a * xr[d]) * w[d] + bia[d];
        im[j] = 0.f;
    }
    wfft512<false>(re, im, tc, ts, lane);
#pragma unroll
    for (int j = 0; j < 8; j++) {
        int d = j * 64 + lane;
        xf[row * 512 + d] = (half2v){(_Float16)re[j], (_Float16)im[j]};
    }
}

// ---------------- k2 : in-place radix-4 2048-pt S-FFT, 2 cols/block ----------------
__device__ __forceinline__ int pidx4(int i) { return i + (i >> 3); }

// Both fwd and inv read the SAME table entry (c,s) = sincos(-2*pi*pos/(4h));
// inv applies the conjugate internally (u = y*(c - i*s)).
__device__ __forceinline__ void r4_fwd(float4* X, int t, int h, const half2v* tw) {
    int pos = t & (h - 1);
    int i = ((t & ~(h - 1)) << 2) | pos;
    int i0 = pidx4(i), i1 = pidx4(i + h), i2 = pidx4(i + 2 * h), i3 = pidx4(i + 3 * h);
    float4 a0 = X[i0], a1 = X[i1], a2 = X[i2], a3 = X[i3];
    half2v wv = tw[pos];
    float c1 = (float)wv.x, s1 = (float)wv.y;
    float c2 = c1 * c1 - s1 * s1, s2 = 2.f * c1 * s1;
    float c3 = c2 * c1 - s2 * s1, s3 = s2 * c1 + c2 * s1;
    float4 o0, o1, o2, o3;
    {
        float t0r = a0.x + a2.x, t0i = a0.y + a2.y, t1r = a0.x - a2.x, t1i = a0.y - a2.y;
        float t2r = a1.x + a3.x, t2i = a1.y + a3.y, t3r = a1.x - a3.x, t3i = a1.y - a3.y;
        o0.x = t0r + t2r; o0.y = t0i + t2i;
        float b1r = t1r + t3i, b1i = t1i - t3r;
        float b2r = t0r - t2r, b2i = t0i - t2i;
        float b3r = t1r - t3i, b3i = t1i + t3r;
        o1.x = b1r * c1 - b1i * s1; o1.y = b1r * s1 + b1i * c1;
        o2.x = b2r * c2 - b2i * s2; o2.y = b2r * s2 + b2i * c2;
        o3.x = b3r * c3 - b3i * s3; o3.y = b3r * s3 + b3i * c3;
    }
    {
        float t0r = a0.z + a2.z, t0i = a0.w + a2.w, t1r = a0.z - a2.z, t1i = a0.w - a2.w;
        float t2r = a1.z + a3.z, t2i = a1.w + a3.w, t3r = a1.z - a3.z, t3i = a1.w - a3.w;
        o0.z = t0r + t2r; o0.w = t0i + t2i;
        float b1r = t1r + t3i, b1i = t1i - t3r;
        float b2r = t0r - t2r, b2i = t0i - t2i;
        float b3r = t1r - t3i, b3i = t1i + t3r;
        o1.z = b1r * c1 - b1i * s1; o1.w = b1r * s1 + b1i * c1;
        o2.z = b2r * c2 - b2i * s2; o2.w = b2r * s2 + b2i * c2;
        o3.z = b3r * c3 - b3i * s3; o3.w = b3r * s3 + b3i * c3;
    }
    X[i0] = o0; X[i1] = o1; X[i2] = o2; X[i3] = o3;
}

__device__ __forceinline__ void r4_inv(float4* X, int t, int h, const half2v* tw) {
    int pos = t & (h - 1);
    int i = ((t & ~(h - 1)) << 2) | pos;
    int i0 = pidx4(i), i1 = pidx4(i + h), i2 = pidx4(i + 2 * h), i3 = pidx4(i + 3 * h);
    float4 y0 = X[i0], y1 = X[i1], y2 = X[i2], y3 = X[i3];
    half2v wv = tw[pos];
    float c1 = (float)wv.x, s1 = (float)wv.y;
    float c2 = c1 * c1 - s1 * s1, s2 = 2.f * c1 * s1;
    float c3 = c2 * c1 - s2 * s1, s3 = s2 * c1 + c2 * s1;
    float4 o0, o1, o2, o3;
    {
        float u1r = y1.x * c1 + y1.y * s1, u1i = y1.y * c1 - y1.x * s1;
        float u2r = y2.x * c2 + y2.y * s2, u2i = y2.y * c2 - y2.x * s2;
        float u3r = y3.x * c3 + y3.y * s3, u3i = y3.y * c3 - y3.x * s3;
        float s0r = y0.x + u2r, s0i = y0.y + u2i;
        float s1r = y0.x - u2r, s1i = y0.y - u2i;
        float s2r = u1r + u3r, s2i = u1i + u3i;
        float s3r = u1r - u3r, s3i = u1i - u3i;
        o0.x = s0r + s2r; o0.y = s0i + s2i;
        o2.x = s0r - s2r; o2.y = s0i - s2i;
        o1.x = s1r - s3i; o1.y = s1i + s3r;
        o3.x = s1r + s3i; o3.y = s1i - s3r;
    }
    {
        float u1r = y1.z * c1 + y1.w * s1, u1i = y1.w * c1 - y1.z * s1;
        float u2r = y2.z * c2 + y2.w * s2, u2i = y2.w * c2 - y2.z * s2;
        float u3r = y3.z * c3 + y3.w * s3, u3i = y3.w * c3 - y3.z * s3;
        float s0r = y0.z + u2r, s0i = y0.w + u2i;
        float s1r = y0.z - u2r, s1i = y0.w - u2i;
        float s2r = u1r + u3r, s2i = u1i + u3i;
        float s3r = u1r - u3r, s3i = u1i - u3i;
        o0.z = s0r + s2r; o0.w = s0i + s2i;
        o2.z = s0r - s2r; o2.w = s0i - s2i;
        o1.z = s1r - s3i; o1.w = s1i + s3r;
        o3.z = s1r + s3i; o3.w = s1i - s3r;
    }
    X[i0] = o0; X[i1] = o1; X[i2] = o2; X[i3] = o3;
}

__global__ __launch_bounds__(512) void k2_sfft(
        half2v* __restrict__ xf,
        const float* __restrict__ qr, const float* __restrict__ qi,
        const float* __restrict__ kr, const float* __restrict__ ki,
        const float* __restrict__ vr, const float* __restrict__ vi,
        const float* __restrict__ rtr, const float* __restrict__ rti) {
    __shared__ float4 buf[2304];
    __shared__ half2v twd[682];   // fwd twiddles: h=512@0, 128@512, 32@640, 8@672, 2@680
    int t = threadIdx.x;
    int g = blockIdx.x;
    int xcd = g & 7, r = g >> 3;
    int pp = xcd * 32 + (r & 31);
    int b = r >> 5;
    int p0 = pp * 2;
    half4v* colh = (half4v*)(xf + (size_t)b * 2048 * 512 + p0);

    // cooperative twiddle-table fill (2 passes over 512 threads)
    for (int i = t; i < 682; i += 512) {
        int h, off;
        if (i < 512)      { h = 512; off = 0; }
        else if (i < 640) { h = 128; off = 512; }
        else if (i < 672) { h = 32;  off = 640; }
        else if (i < 680) { h = 8;   off = 672; }
        else              { h = 2;   off = 680; }
        int pos = i - off;
        float s, c;
        __sincosf(-6.28318530717958647692f * (float)pos / (float)(4 * h), &s, &c);
        twd[i] = (half2v){(_Float16)c, (_Float16)s};
    }

#pragma unroll
    for (int c = 0; c < 4; c++) {
        int s = t + 512 * c;
        half4v h = colh[(size_t)s * 256];
        buf[pidx4(s)] = make_float4((float)h.x, (float)h.y, (float)h.z, (float)h.w);
    }
    __syncthreads(); r4_fwd(buf, t, 512, twd);
    __syncthreads(); r4_fwd(buf, t, 128, twd + 512);
    __syncthreads(); r4_fwd(buf, t, 32, twd + 640);
    __syncthreads(); r4_fwd(buf, t, 8, twd + 672);
    __syncthreads(); r4_fwd(buf, t, 2, twd + 680);
    __syncthreads();
#pragma unroll
    for (int c = 0; c < 2; c++) {
        int pr = t + 512 * c;
        int ia = pidx4(2 * pr), ib = pidx4(2 * pr + 1);
        float4 a = buf[ia], bb = buf[ib];
        buf[ia] = make_float4(a.x + bb.x, a.y + bb.y, a.z + bb.z, a.w + bb.w);
        buf[ib] = make_float4(a.x - bb.x, a.y - bb.y, a.z - bb.z, a.w - bb.w);
    }
    __syncthreads();

    int f0 = __brev((unsigned)p0) >> 23;
    int f1 = __brev((unsigned)(p0 + 1)) >> 23;
    float qw0r = qr[f0], qw0i = qi[f0], kw0r = kr[f0], kw0i = ki[f0], vw0r = vr[f0], vw0i = vi[f0];
    float qw1r = qr[f1], qw1i = qi[f1], kw1r = kr[f1], kw1i = ki[f1], vw1r = vr[f1], vw1i = vi[f1];
#pragma unroll
    for (int c = 0; c < 4; c++) {
        int idx = pidx4(t + 512 * c);
        float4 y = buf[idx];
        {
            float yr = y.x, yi = y.y;
            float qre = yr * qw0r - yi * qw0i, qim = yr * qw0i + yi * qw0r;
            float kre = yr * kw0r - yi * kw0i + 1e-12f, kim = yr * kw0i + yi * kw0r;
            float vre = yr * vw0r - yi * vw0i, vim = yr * vw0i + yi * vw0r;
            float inv = 1.0f / (kre * kre + kim * kim);
            float dre = (qre * kre + qim * kim) * inv;
            float dim = (qim * kre - qre * kim) * inv;
            y.x = dre * vre - dim * vim;
            y.y = dre * vim + dim * vre;
        }
        {
            float yr = y.z, yi = y.w;
            float qre = yr * qw1r - yi * qw1i, qim = yr * qw1i + yi * qw1r;
            float kre = yr * kw1r - yi * kw1i + 1e-12f, kim = yr * kw1i + yi * kw1r;
            float vre = yr * vw1r - yi * vw1i, vim = yr * vw1i + yi * vw1r;
            float inv = 1.0f / (kre * kre + kim * kim);
            float dre = (qre * kre + qim * kim) * inv;
            float dim = (qim * kre - qre * kim) * inv;
            y.z = dre * vre - dim * vim;
            y.w = dre * vim + dim * vre;
        }
        buf[idx] = y;
    }

    __syncthreads();
#pragma unroll
    for (int c = 0; c < 2; c++) {
        int pr = t + 512 * c;
        int ia = pidx4(2 * pr), ib = pidx4(2 * pr + 1);
        float4 a = buf[ia], bb = buf[ib];
        buf[ia] = make_float4(a.x + bb.x, a.y + bb.y, a.z + bb.z, a.w + bb.w);
        buf[ib] = make_float4(a.x - bb.x, a.y - bb.y, a.z - bb.z, a.w - bb.w);
    }
    __syncthreads(); r4_inv(buf, t, 2, twd + 680);
    __syncthreads(); r4_inv(buf, t, 8, twd + 672);
    __syncthreads(); r4_inv(buf, t, 32, twd + 640);
    __syncthreads(); r4_inv(buf, t, 128, twd + 512);
    __syncthreads(); r4_inv(buf, t, 512, twd);
    __syncthreads();

    const float sc = 1.0f / 2048.0f;
    float r0r = rtr[f0] * sc, r0i = rti[f0] * sc;
    float r1r = rtr[f1] * sc, r1i = rti[f1] * sc;
#pragma unroll
    for (int c = 0; c < 4; c++) {
        int s = t + 512 * c;
        float4 z = buf[pidx4(s)];
        float ox = z.x * r0r - z.y * r0i, oy = z.x * r0i + z.y * r0r;
        float oz = z.z * r1r - z.w * r1i, ow = z.z * r1i + z.w * r1r;
        colh[(size_t)s * 256] = (half4v){(_Float16)ox, (_Float16)oy, (_Float16)oz, (_Float16)ow};
    }
}

// ---------------- k3 : row-pair residual + dyt_b + q/k (Parseval-packed) + v ----------------
__global__ __launch_bounds__(256) void k3_mid(
        const half2v* __restrict__ xf,
        const float* __restrict__ x,
        const float* __restrict__ alpha, const float* __restrict__ w, const float* __restrict__ bia,
        const float* __restrict__ qr, const float* __restrict__ qi,
        const float* __restrict__ kr, const float* __restrict__ ki,
        const float* __restrict__ vr, const float* __restrict__ vi,
        float* __restrict__ x1,
        unsigned short* __restrict__ qb, unsigned short* __restrict__ kb, unsigned short* __restrict__ vb) {
    __shared__ __align__(16) char smem[4 * 1024 * 8];  // 32KB
    int tid = threadIdx.x, lane = tid & 63, wv = tid >> 6;
    float2* zb = (float2*)(smem + wv * 8192);          // phase1: wave-private 8KB
    float* wbs = (float*)smem;                          // [6][512]=12KB (after combine)
    float2* zf = (float2*)(smem + 12288 + wv * 4096);  // phase2: wave-private 4KB
    size_t pr = (size_t)blockIdx.x * 4 + wv;
    size_t r1 = pr * 2, r2 = r1 + 1;
    float tc[12], ts[12];
    wtw512(tc, ts, lane);

    float xa[8], xb2[8];
#pragma unroll
    for (int j = 0; j < 8; j++) {
        int d = j * 64 + lane;
        half2v h1 = xf[r1 * 512 + d];
        half2v h2 = xf[r2 * 512 + d];
        zb[d]       = make_float2((float)h1.x, (float)h1.y);
        zb[512 + d] = make_float2((float)h2.x, (float)h2.y);
        xa[j]  = x[r1 * 512 + d];
        xb2[j] = x[r2 * 512 + d];
    }
    float re[8], im[8];
#pragma unroll
    for (int j = 0; j < 8; j++) {
        int d = j * 64 + lane;
        int fd = __brev((unsigned)d) >> 23;
        int dp = __brev((unsigned)((512 - fd) & 511)) >> 23;
        float2 z1 = zb[d], z1p = zb[dp];
        float2 z2 = zb[512 + d], z2p = zb[512 + dp];
        float h1r = 0.5f * (z1.x + z1p.x), h1i = 0.5f * (z1.y - z1p.y);
        float h2r = 0.5f * (z2.x + z2p.x), h2i = 0.5f * (z2.y - z2p.y);
        re[j] = h1r - h2i;
        im[j] = h1i + h2r;
    }
    __syncthreads();
    for (int idx = tid; idx < 512; idx += 256) {
        int f = __brev((unsigned)idx) >> 23;
        int gg = (512 - f) & 511;
        float aa = (f == 0 || f == 256) ? 0.04419417382415922f : 0.0625f;
        float ah = aa * 0.5f;
        const float s5 = 0.5f * (1.0f / 512.0f);
        wbs[0 * 512 + idx] = ah * (qr[f] + qr[gg]); wbs[1 * 512 + idx] = ah * (qi[f] - qi[gg]);
        wbs[2 * 512 + idx] = ah * (kr[f] + kr[gg]); wbs[3 * 512 + idx] = ah * (ki[f] - ki[gg]);
        wbs[4 * 512 + idx] = s5 * (vr[f] + vr[gg]); wbs[5 * 512 + idx] = s5 * (vi[f] - vi[gg]);
    }

    wfft512<true>(re, im, tc, ts, lane);
    float a = alpha[0];
    float gre[8], gim[8];
#pragma unroll
    for (int j = 0; j < 8; j++) {
        int d = j * 64 + lane;
        float v1 = re[j] * (1.0f / 512.0f) + xa[j];
        float v2 = im[j] * (1.0f / 512.0f) + xb2[j];
        x1[r1 * 512 + d] = v1;
        x1[r2 * 512 + d] = v2;
        gre[j] = dyt_tanh(a * v1) * w[d] + bia[d];
        gim[j] = dyt_tanh(a * v2) * w[d] + bia[d];
    }
    wfft512<false>(gre, gim, tc, ts, lane);
    __syncthreads();

#pragma unroll
    for (int j = 0; j < 8; j++)
        zf[j * 64 + lane] = make_float2(gre[j], gim[j]);

    float pvr[8], pvi[8];
#pragma unroll
    for (int j = 0; j < 8; j++) {
        int i = j * 64 + lane;
        float wr0 = wbs[4 * 512 + i], wi0 = wbs[5 * 512 + i];
        pvr[j] = gre[j] * wr0 - gim[j] * wi0;
        pvi[j] = gre[j] * wi0 + gim[j] * wr0;
    }

    bool odd = (lane & 1) != 0;
#pragma unroll
    for (int j = 0; j < 8; j++) {
        int d = j * 64 + lane;
        int fd = __brev((unsigned)d) >> 23;
        int dp = __brev((unsigned)((512 - fd) & 511)) >> 23;
        float2 Zp = zf[dp];
        float zr = gre[j], zi = gim[j];
        float A1r = 0.5f * (zr + Zp.x), A1i = 0.5f * (zi - Zp.y);
        float A2r = 0.5f * (zi + Zp.y), A2i = 0.5f * (Zp.x - zr);
        float wr0 = wbs[0 * 512 + d], wi0 = wbs[1 * 512 + d];
        float Q1r = A1r * wr0 - A1i * wi0, Q1i = A1r * wi0 + A1i * wr0;
        float Q2r = A2r * wr0 - A2i * wi0, Q2i = A2r * wi0 + A2i * wr0;
        qb[r1 * 512 + d] = f2bf(odd ? -Q1i : Q1r);
        qb[r2 * 512 + d] = f2bf(odd ? -Q2i : Q2r);
        float wr1 = wbs[2 * 512 + d], wi1 = wbs[3 * 512 + d];
        float K1r = A1r * wr1 - A1i * wi1, K1i = A1r * wi1 + A1i * wr1;
        float K2r = A2r * wr1 - A2i * wi1, K2i = A2r * wi1 + A2i * wr1;
        kb[r1 * 512 + d] = f2bf(odd ? -K1i : K1r);
        kb[r2 * 512 + d] = f2bf(odd ? -K2i : K2r);
    }

    wfft512<true>(pvr, pvi, tc, ts, lane);
#pragma unroll
    for (int j = 0; j < 8; j++) {
        int d = j * 64 + lane;
        vb[r1 * 512 + d] = f2bf(pvr[j]);
        vb[r2 * 512 + d] = f2bf(pvi[j]);
    }
}

// ---------------- unified bt-GEMM (BK=64, global_load_lds, XOR-swizzled LDS) ----------------
__global__ __launch_bounds__(256) void gemm_bt(
        const unsigned short* __restrict__ A, const unsigned short* __restrict__ Bt,
        void* __restrict__ C, int M, int N, int Ks, int kseg, float scale, int out_half) {
    int tilesM = M >> 7, tilesN = N >> 7;
    int perBatch = tilesM * tilesN;
    int l = blockIdx.x;
    int seg = blockIdx.y;
    int s = l & 7, t = l >> 3;
    int cnt = perBatch >> 3;
    int bz = t / cnt;
    int u = t - bz * cnt;
    int pn = tilesN >> 1, pm = tilesM >> 2;
    int n0 = ((s & 1) * pn + (u % pn)) << 7;
    int m0 = ((s >> 1) * pm + (u / pn)) << 7;
    int kbase = seg * kseg;

    const unsigned short* Ab = A + (size_t)bz * M * Ks;
    const unsigned short* Bb = Bt + (size_t)bz * N * Ks;
    __shared__ __align__(16) unsigned short smem[2 * 128 * 64];
    unsigned short* As = smem;
    unsigned short* Bs = smem + 128 * 64;
    int tid = threadIdx.x;
    int wave = tid >> 6, lane = tid & 63;
    int wm = (wave >> 1) * 64, wn = (wave & 1) * 64;
    int lrow = lane & 15, lq = lane >> 4;
    floatx4 acc[4][4];
#pragma unroll
    for (int i = 0; i < 4; i++)
#pragma unroll
        for (int j = 0; j < 4; j++)
            acc[i][j] = (floatx4){0.f, 0.f, 0.f, 0.f};

    int lr = lane >> 3;
    int lcs = lane & 7;
    for (int k0 = kbase; k0 < kbase + kseg; k0 += 64) {
        __syncthreads();
#pragma unroll
        for (int i = 0; i < 4; i++) {
            int c = wave * 4 + i;
            int r = c * 8 + lr;
            int gcol = ((lcs ^ (r & 7)) << 3);
            async_load16(Ab + (size_t)(m0 + r) * Ks + k0 + gcol, As + c * 512);
            async_load16(Bb + (size_t)(n0 + r) * Ks + k0 + gcol, Bs + c * 512);
        }
        __syncthreads();
        bf16x8 a0[4], a1[4], b0[4], b1[4];
#pragma unroll
        for (int mi = 0; mi < 4; mi++) {
            int r = wm + mi * 16 + lrow;
            a0[mi] = *(const bf16x8*)(As + r * 64 + ((lq ^ (r & 7)) << 3));
            a1[mi] = *(const bf16x8*)(As + r * 64 + (((lq + 4) ^ (r & 7)) << 3));
        }
#pragma unroll
        for (int ni = 0; ni < 4; ni++) {
            int r = wn + ni * 16 + lrow;
            b0[ni] = *(const bf16x8*)(Bs + r * 64 + ((lq ^ (r & 7)) << 3));
            b1[ni] = *(const bf16x8*)(Bs + r * 64 + (((lq + 4) ^ (r & 7)) << 3));
        }
#pragma unroll
        for (int mi = 0; mi < 4; mi++)
#pragma unroll
            for (int ni = 0; ni < 4; ni++) {
                acc[mi][ni] = __builtin_amdgcn_mfma_f32_16x16x32_bf16(a0[mi], b0[ni], acc[mi][ni], 0, 0, 0);
                acc[mi][ni] = __builtin_amdgcn_mfma_f32_16x16x32_bf16(a1[mi], b1[ni], acc[mi][ni], 0, 0, 0);
            }
    }
    size_t cbase = ((size_t)seg * 4 + bz) * (size_t)M * N;
    int lr0 = (wave >> 1) * 16 + lq * 4;
    for (int mi = 0; mi < 4; mi++) {
        __syncthreads();
        if (out_half) {
            _Float16* Cs = (_Float16*)smem;
            for (int ni = 0; ni < 4; ni++)
                for (int r = 0; r < 4; r++)
                    Cs[(lr0 + r) * 128 + wn + ni * 16 + lrow] = (_Float16)(acc[mi][ni][r] * scale);
            __syncthreads();
            for (int h = 0; h < 2; h++) {
                int chunk = tid + h * 256;
                int rl = chunk >> 4, cb = (chunk & 15) * 16;
                int grow = m0 + mi * 16 + (rl & 15) + (rl >> 4) * 64;
                *(uint4*)((char*)C + (cbase + (size_t)grow * N + n0) * 2 + cb) =
                    *(const uint4*)((const char*)Cs + rl * 256 + cb);
            }
        } else {
            float* Cs = (float*)smem;
            for (int ni = 0; ni < 4; ni++)
                for (int r = 0; r < 4; r++)
                    Cs[(lr0 + r) * 128 + wn + ni * 16 + lrow] = acc[mi][ni][r] * scale;
            __syncthreads();
            for (int h = 0; h < 4; h++) {
                int chunk = tid + h * 256;
                int rl = chunk >> 5, cb = (chunk & 31) * 16;
                int grow = m0 + mi * 16 + (rl & 15) + (rl >> 4) * 64;
                *(uint4*)((char*)C + (cbase + (size_t)grow * N + n0) * 4 + cb) =
                    *(const uint4*)((const char*)Cs + rl * 512 + cb);
            }
        }
    }
}

// ---------------- softmax (in-place bf16 P) + v->vT transpose, one grid ----------------
__global__ __launch_bounds__(256) void sm_tr(
        const _Float16* __restrict__ Sc, unsigned short* __restrict__ P,
        const unsigned short* __restrict__ vb, unsigned short* __restrict__ vT) {
    __shared__ __align__(16) char lds[64 * 65 * 2];  // transpose tile; softmax uses first 16B
    if (blockIdx.x < 8192) {
        float* red = (float*)lds;
        int tid = threadIdx.x;
        size_t row = blockIdx.x;
        halfx8 hv = *(const halfx8*)(Sc + row * 2048 + tid * 8);
        float v[8];
#pragma unroll
        for (int j = 0; j < 8; j++) v[j] = (float)hv[j];
        float mx = v[0];
#pragma unroll
        for (int j = 1; j < 8; j++) mx = fmaxf(mx, v[j]);
        for (int off = 32; off >= 1; off >>= 1) mx = fmaxf(mx, __shfl_xor(mx, off));
        int wv = tid >> 6;
        if ((tid & 63) == 0) red[wv] = mx;
        __syncthreads();
        mx = fmaxf(fmaxf(red[0], red[1]), fmaxf(red[2], red[3]));
        float e[8], sum = 0.f;
#pragma unroll
        for (int j = 0; j < 8; j++) { e[j] = __expf(v[j] - mx); sum += e[j]; }
        for (int off = 32; off >= 1; off >>= 1) sum += __shfl_xor(sum, off);
        __syncthreads();
        if ((tid & 63) == 0) red[wv] = sum;
        __syncthreads();
        float inv = 1.0f / (red[0] + red[1] + red[2] + red[3]);
        ushortx8 o;
#pragma unroll
        for (int j = 0; j < 8; j++) o[j] = f2bf(e[j] * inv);
        *(ushortx8*)(P + row * 2048 + tid * 8) = o;
    } else {
        unsigned short (*tile)[65] = (unsigned short (*)[65])lds;
        int id = blockIdx.x - 8192;           // 1024 transpose blocks: (32, 8, 4)
        int sx = id & 31, dy = (id >> 5) & 7, bz = id >> 8;
        int s0 = sx * 64, d0 = dy * 64;
        int tx = threadIdx.x & 63, ty = threadIdx.x >> 6;
        for (int j = 0; j < 16; j++) {
            int s = ty + j * 4;
            tile[s][tx] = vb[((size_t)bz * 2048 + s0 + s) * 512 + d0 + tx];
        }
        __syncthreads();
        for (int j = 0; j < 16; j++) {
            int d = ty + j * 4;
            vT[((size_t)bz * 512 + d0 + d) * 2048 + s0 + tx] = tile[tx][d];
        }
    }
}

// ---------------- k5 : row-pair residual + dyt_f + spectral filter ----------------
// R22: sums FOUR fp16 split-K partials (attnP + p*SEGSZ).
__global__ __launch_bounds__(256) void k5_ffn(
        const _Float16* __restrict__ attnP,
        const float* __restrict__ x1,
        const float* __restrict__ alpha, const float* __restrict__ w, const float* __restrict__ bia,
        const float* __restrict__ br, const float* __restrict__ bi,
        float* __restrict__ out) {
    const size_t SEGSZ = (size_t)4 * 2048 * 512;
    __shared__ float wbs[2][512];
    int tid = threadIdx.x, lane = tid & 63, wv = tid >> 6;
    size_t pr = (size_t)blockIdx.x * 4 + wv;
    size_t r1 = pr * 2, r2 = r1 + 1;
    for (int idx = tid; idx < 512; idx += 256) {
        int f = __brev((unsigned)idx) >> 23;
        int gg = (512 - f) & 511;
        wbs[0][idx] = 0.5f * (br[f] + br[gg]) * (1.0f / 512.0f);
        wbs[1][idx] = 0.5f * (bi[f] - bi[gg]) * (1.0f / 512.0f);
    }
    float tc[12], ts[12];
    wtw512(tc, ts, lane);
    float a = alpha[0];
    float re[8], im[8], x2a[8], x2b[8];
#pragma unroll
    for (int j = 0; j < 8; j++) {
        int d = j * 64 + lane;
        float v1 = x1[r1 * 512 + d];
        float v2 = x1[r2 * 512 + d];
#pragma unroll
        for (int p = 0; p < 4; p++) {
            v1 += (float)attnP[p * SEGSZ + r1 * 512 + d];
            v2 += (float)attnP[p * SEGSZ + r2 * 512 + d];
        }
        x2a[j] = v1; x2b[j] = v2;
        re[j] = dyt_tanh(a * v1) * w[d] + bia[d];
        im[j] = dyt_tanh(a * v2) * w[d] + bia[d];
    }
    wfft512<false>(re, im, tc, ts, lane);
    __syncthreads();
#pragma unroll
    for (int j = 0; j < 8; j++) {
        int i = j * 64 + lane;
        float wr0 = wbs[0][i], wi0 = wbs[1][i];
        float rr = re[j], ii = im[j];
        re[j] = rr * wr0 - ii * wi0;
        im[j] = rr * wi0 + ii * wr0;
    }
    wfft512<true>(re, im, tc, ts, lane);
#pragma unroll
    for (int j = 0; j < 8; j++) {
        int d = j * 64 + lane;
        out[r1 * 512 + d] = re[j] + x2a[j];
        out[r2 * 512 + d] = im[j] + x2b[j];
    }
}

extern "C" void kernel_launch(void* const* d_in, const int* in_sizes, int n_in,
                              void* d_out, int out_size, void* d_ws, size_t ws_size,
                              hipStream_t stream) {
    const float* x      = (const float*)d_in[0];
    const float* a_qr   = (const float*)d_in[1];
    const float* a_kr   = (const float*)d_in[2];
    const float* a_vr   = (const float*)d_in[3];
    const float* a_rtr  = (const float*)d_in[4];
    const float* b_qr   = (const float*)d_in[5];
    const float* b_kr   = (const float*)d_in[6];
    const float* b_vr   = (const float*)d_in[7];
    /* f_ar = d_in[8] unused (dead gelu branch) */
    const float* f_br   = (const float*)d_in[9];
    const float* a_qi   = (const float*)d_in[10];
    const float* a_ki   = (const float*)d_in[11];
    const float* a_vi   = (const float*)d_in[12];
    const float* a_rti  = (const float*)d_in[13];
    const float* b_qi   = (const float*)d_in[14];
    const float* b_ki   = (const float*)d_in[15];
    const float* b_vi   = (const float*)d_in[16];
    /* f_ai = d_in[17] unused */
    const float* f_bi   = (const float*)d_in[18];
    /* f_bias = d_in[19] unused (dead gelu branch) */
    const float* dyta_alpha = (const float*)d_in[20];
    const float* dyta_w     = (const float*)d_in[21];
    const float* dyta_b     = (const float*)d_in[22];
    const float* dytb_alpha = (const float*)d_in[23];
    const float* dytb_w     = (const float*)d_in[24];
    const float* dytb_b     = (const float*)d_in[25];
    const float* dytf_alpha = (const float*)d_in[26];
    const float* dytf_w     = (const float*)d_in[27];
    const float* dytf_b     = (const float*)d_in[28];
    (void)in_sizes; (void)n_in; (void)out_size; (void)ws_size;

    char* ws = (char*)d_ws;
    const size_t MB = 1024 * 1024;
    half2v* xfH = (half2v*)(ws + 0 * MB);           // 16MB packed fp16 complex
    float* x1   = (float*)(ws + 32 * MB);           // 16MB
    unsigned short* qb = (unsigned short*)(ws + 48 * MB);  // 8MB
    unsigned short* kb = (unsigned short*)(ws + 56 * MB);  // 8MB
    unsigned short* vb = (unsigned short*)(ws + 64 * MB);  // 8MB
    unsigned short* vT = (unsigned short*)(ws + 72 * MB);  // 8MB
    _Float16* scores   = (_Float16*)(ws + 0 * MB);  // 32MB, overlays dead xfH
    unsigned short* Pb = (unsigned short*)(ws + 0 * MB);   // bf16 P, in place over scores
    _Float16* attnP    = (_Float16*)(ws + 81 * MB); // 32MB: four 8MB fp16 K-split partials
    float* outp = (float*)d_out;

    k1_dyt_fftd<<<2048, 256, 0, stream>>>(x, dyta_alpha, dyta_w, dyta_b, xfH);
    k2_sfft<<<1024, 512, 0, stream>>>(xfH, a_qr, a_qi, a_kr, a_ki, a_vr, a_vi, a_rtr, a_rti);
    k3_mid<<<1024, 256, 0, stream>>>(xfH, x, dytb_alpha, dytb_w, dytb_b,
                                     b_qr, b_qi, b_kr, b_ki, b_vr, b_vi, x1, qb, kb, vb);
    gemm_bt<<<1024, 256, 0, stream>>>(qb, kb, scores, 2048, 2048, 512, 512,
                                      0.04419417382415922f, 1);
    sm_tr<<<9216, 256, 0, stream>>>(scores, Pb, vb, vT);
    gemm_bt<<<dim3(256, 4), 256, 0, stream>>>(Pb, vT, attnP, 2048, 512, 2048, 512,
                                              1.0f, 1);
    k5_ffn<<<1024, 256, 0, stream>>>(attnP, x1,
                                     dytf_alpha, dytf_w, dytf_b, f_br, f_bi, outp);
}

// Round 6
// 282.669 us; speedup vs baseline: 1.0365x; 1.0142x over previous
//
#include <hip/hip_runtime.h>

// B=4, S=2048, D=512, fp32 in/out. threshold 1.45e-1.
// Pipeline (Hermitian-packed D-FFTs: one 512-pt FFT serves TWO rows):
//  k1 : u=dyt_a(x); XfH = FFT_D(u)          (wave-register FFT, bitrev bins, half2 storage)
//  k2 : per column-PAIR: in-place radix-4 2048-pt S-FFT (fp32 LDS, fp16 global),
//       spectral op, exact inverse, *rtw/S. Twiddles from a 682-entry LDS table.
//  k3 : per ROW-PAIR: Hermitian combine, x1, dyt_b; q,k Parseval-packed in the
//       frequency domain (no inverse FFTs); v packed inverse FFT.
//  g1 : scores = q@k^T
//  smtr: full softmax per row written in place as bf16 P + v->vT transpose.
//  g2 : attn = P@vT, split-K x2 (R23: back to x2 -- R22's x4 was +2.5us),
//       fp16 partials (kept: minimum-traffic variant, never isolated before).
//  k5 : row-pair packed dyt_f + spectral filter (sums TWO fp16 partials)
// R23 consolidation: R19-exact structure (best measured, 284.2us) + fp16
// partials alone (-32MB traffic). GEMM-side lesson from R20-R22: dbuf/splitK
// variants all within +-3us -> attn GEMMs are not a large wall-time fraction.
// k3 lesson (R21): serial-chain LATENCY bound -- do not add VALU to the
// shuffle chain; occupancy structurally capped at 4 waves/SIMD.

typedef __attribute__((ext_vector_type(8))) __bf16 bf16x8;
typedef __attribute__((ext_vector_type(4))) float floatx4;
typedef __attribute__((ext_vector_type(8))) _Float16 halfx8;
typedef __attribute__((ext_vector_type(8))) unsigned short ushortx8;
typedef __attribute__((ext_vector_type(2))) _Float16 half2v;   // 4B packed complex (re,im)
typedef __attribute__((ext_vector_type(4))) _Float16 half4v;   // 8B = two packed complex

__device__ __forceinline__ unsigned short f2bf(float x) {
    unsigned u = __float_as_uint(x);
    u = (u + 0x7fffu + ((u >> 16) & 1u)) >> 16;
    return (unsigned short)u;
}

__device__ __forceinline__ float dyt_tanh(float x) {
    float e = __expf(2.0f * x);
    return 1.0f - 2.0f / (e + 1.0f);
}

__device__ __forceinline__ void async_load16(const unsigned short* g, unsigned short* l) {
    __builtin_amdgcn_global_load_lds(
        (const __attribute__((address_space(1))) unsigned int*)g,
        (__attribute__((address_space(3))) unsigned int*)l, 16, 0, 0);
}

// ---------- wave-level 512-pt FFT (8 pts/lane) ----------
__device__ __forceinline__ void wtw512(float (&tc)[12], float (&ts)[12], int lane) {
    const float w = -6.28318530717958647692f / 512.0f;
#pragma unroll
    for (int j = 0; j < 4; j++) __sincosf(w * (float)(j * 64 + lane), &ts[j], &tc[j]);
#pragma unroll
    for (int j = 0; j < 2; j++) __sincosf(w * (float)(2 * (j * 64 + lane)), &ts[4 + j], &tc[4 + j]);
    __sincosf(w * (float)(4 * lane), &ts[6], &tc[6]);
    __sincosf(w * (float)(8 * (lane & 31)), &ts[7], &tc[7]);
    __sincosf(w * (float)(16 * (lane & 15)), &ts[8], &tc[8]);
    __sincosf(w * (float)(32 * (lane & 7)), &ts[9], &tc[9]);
    __sincosf(w * (float)(64 * (lane & 3)), &ts[10], &tc[10]);
    __sincosf(w * (float)(128 * (lane & 1)), &ts[11], &tc[11]);
}

template <bool INV>
__device__ __forceinline__ void wfft512(float (&re)[8], float (&im)[8],
                                        const float (&tc)[12], const float (&ts)[12], int lane) {
    if (!INV) {
#pragma unroll
        for (int j = 0; j < 4; j++) {
            float ur = re[j], ui = im[j], vr = re[j + 4], vi = im[j + 4];
            re[j] = ur + vr; im[j] = ui + vi;
            float dr = ur - vr, di = ui - vi;
            re[j + 4] = dr * tc[j] - di * ts[j];
            im[j + 4] = dr * ts[j] + di * tc[j];
        }
#pragma unroll
        for (int g = 0; g < 8; g += 4)
#pragma unroll
            for (int jj = 0; jj < 2; jj++) {
                int j = g + jj;
                float ur = re[j], ui = im[j], vr = re[j + 2], vi = im[j + 2];
                re[j] = ur + vr; im[j] = ui + vi;
                float dr = ur - vr, di = ui - vi;
                re[j + 2] = dr * tc[4 + jj] - di * ts[4 + jj];
                im[j + 2] = dr * ts[4 + jj] + di * tc[4 + jj];
            }
#pragma unroll
        for (int j = 0; j < 8; j += 2) {
            float ur = re[j], ui = im[j], vr = re[j + 1], vi = im[j + 1];
            re[j] = ur + vr; im[j] = ui + vi;
            float dr = ur - vr, di = ui - vi;
            re[j + 1] = dr * tc[6] - di * ts[6];
            im[j + 1] = dr * ts[6] + di * tc[6];
        }
#pragma unroll
        for (int st = 0; st < 6; st++) {
            int h = 32 >> st;
            bool hi = (lane & h) != 0;
            float c = (st < 5) ? tc[7 + st] : 1.0f;
            float s = (st < 5) ? ts[7 + st] : 0.0f;
#pragma unroll
            for (int j = 0; j < 8; j++) {
                float orr = __shfl_xor(re[j], h, 64);
                float oii = __shfl_xor(im[j], h, 64);
                float dr = orr - re[j], di = oii - im[j];
                float sr = re[j] + orr, si = im[j] + oii;
                re[j] = hi ? (dr * c - di * s) : sr;
                im[j] = hi ? (dr * s + di * c) : si;
            }
        }
    } else {
#pragma unroll
        for (int st = 5; st >= 0; st--) {
            int h = 32 >> st;
            bool hi = (lane & h) != 0;
            float c = (st < 5) ? tc[7 + st] : 1.0f;
            float s = (st < 5) ? ts[7 + st] : 0.0f;
#pragma unroll
            for (int j = 0; j < 8; j++) {
                float zr = re[j], zi = im[j];
                float vr = zr * c + zi * s;
                float vi = zi * c - zr * s;
                float mr = hi ? vr : zr;
                float mi = hi ? vi : zi;
                float orr = __shfl_xor(mr, h, 64);
                float oii = __shfl_xor(mi, h, 64);
                re[j] = hi ? (orr - vr) : (zr + orr);
                im[j] = hi ? (oii - vi) : (zi + oii);
            }
        }
#pragma unroll
        for (int j = 0; j < 8; j += 2) {
            float vr = re[j + 1] * tc[6] + im[j + 1] * ts[6];
            float vi = im[j + 1] * tc[6] - re[j + 1] * ts[6];
            re[j + 1] = re[j] - vr; im[j + 1] = im[j] - vi;
            re[j] += vr; im[j] += vi;
        }
#pragma unroll
        for (int g = 0; g < 8; g += 4)
#pragma unroll
            for (int jj = 0; jj < 2; jj++) {
                int j = g + jj;
                float vr = re[j + 2] * tc[4 + jj] + im[j + 2] * ts[4 + jj];
                float vi = im[j + 2] * tc[4 + jj] - re[j + 2] * ts[4 + jj];
                re[j + 2] = re[j] - vr; im[j + 2] = im[j] - vi;
                re[j] += vr; im[j] += vi;
            }
#pragma unroll
        for (int j = 0; j < 4; j++) {
            float vr = re[j + 4] * tc[j] + im[j + 4] * ts[j];
            float vi = im[j + 4] * tc[j] - re[j + 4] * ts[j];
            re[j + 4] = re[j] - vr; im[j + 4] = im[j] - vi;
            re[j] += vr; im[j] += vi;
        }
    }
}

// ---------------- k1 : dyt_a + forward D-FFT (half2 output) ----------------
__global__ __launch_bounds__(256) void k1_dyt_fftd(
        const float* __restrict__ x,
        const float* __restrict__ alpha, const float* __restrict__ w, const float* __restrict__ bia,
        half2v* __restrict__ xf) {
    int tid = threadIdx.x, lane = tid & 63, wv = tid >> 6;
    size_t row = (size_t)blockIdx.x * 4 + wv;
    float tc[12], ts[12];
    wtw512(tc, ts, lane);
    float re[8], im[8];
    float a = alpha[0];
    const float* xr = x + row * 512;
#pragma unroll
    for (int j = 0; j < 8; j++) {
        int d = j * 64 + lane;
        re[j] = dyt_tanh(a * xr[d]) * w[d] + bia[d];
        im[j] = 0.f;
    }
    wfft512<false>(re, im, tc, ts, lane);
#pragma unroll
    for (int j = 0; j < 8; j++) {
        int d = j * 64 + lane;
        xf[row * 512 + d] = (half2v){(_Float16)re[j], (_Float16)im[j]};
    }
}

// ---------------- k2 : in-place radix-4 2048-pt S-FFT, 2 cols/block ----------------
__device__ __forceinline__ int pidx4(int i) { return i + (i >> 3); }

// Both fwd and inv read the SAME table entry (c,s) = sincos(-2*pi*pos/(4h));
// inv applies the conjugate internally (u = y*(c - i*s)).
__device__ __forceinline__ void r4_fwd(float4* X, int t, int h, const half2v* tw) {
    int pos = t & (h - 1);
    int i = ((t & ~(h - 1)) << 2) | pos;
    int i0 = pidx4(i), i1 = pidx4(i + h), i2 = pidx4(i + 2 * h), i3 = pidx4(i + 3 * h);
    float4 a0 = X[i0], a1 = X[i1], a2 = X[i2], a3 = X[i3];
    half2v wv = tw[pos];
    float c1 = (float)wv.x, s1 = (float)wv.y;
    float c2 = c1 * c1 - s1 * s1, s2 = 2.f * c1 * s1;
    float c3 = c2 * c1 - s2 * s1, s3 = s2 * c1 + c2 * s1;
    float4 o0, o1, o2, o3;
    {
        float t0r = a0.x + a2.x, t0i = a0.y + a2.y, t1r = a0.x - a2.x, t1i = a0.y - a2.y;
        float t2r = a1.x + a3.x, t2i = a1.y + a3.y, t3r = a1.x - a3.x, t3i = a1.y - a3.y;
        o0.x = t0r + t2r; o0.y = t0i + t2i;
        float b1r = t1r + t3i, b1i = t1i - t3r;
        float b2r = t0r - t2r, b2i = t0i - t2i;
        float b3r = t1r - t3i, b3i = t1i + t3r;
        o1.x = b1r * c1 - b1i * s1; o1.y = b1r * s1 + b1i * c1;
        o2.x = b2r * c2 - b2i * s2; o2.y = b2r * s2 + b2i * c2;
        o3.x = b3r * c3 - b3i * s3; o3.y = b3r * s3 + b3i * c3;
    }
    {
        float t0r = a0.z + a2.z, t0i = a0.w + a2.w, t1r = a0.z - a2.z, t1i = a0.w - a2.w;
        float t2r = a1.z + a3.z, t2i = a1.w + a3.w, t3r = a1.z - a3.z, t3i = a1.w - a3.w;
        o0.z = t0r + t2r; o0.w = t0i + t2i;
        float b1r = t1r + t3i, b1i = t1i - t3r;
        float b2r = t0r - t2r, b2i = t0i - t2i;
        float b3r = t1r - t3i, b3i = t1i + t3r;
        o1.z = b1r * c1 - b1i * s1; o1.w = b1r * s1 + b1i * c1;
        o2.z = b2r * c2 - b2i * s2; o2.w = b2r * s2 + b2i * c2;
        o3.z = b3r * c3 - b3i * s3; o3.w = b3r * s3 + b3i * c3;
    }
    X[i0] = o0; X[i1] = o1; X[i2] = o2; X[i3] = o3;
}

__device__ __forceinline__ void r4_inv(float4* X, int t, int h, const half2v* tw) {
    int pos = t & (h - 1);
    int i = ((t & ~(h - 1)) << 2) | pos;
    int i0 = pidx4(i), i1 = pidx4(i + h), i2 = pidx4(i + 2 * h), i3 = pidx4(i + 3 * h);
    float4 y0 = X[i0], y1 = X[i1], y2 = X[i2], y3 = X[i3];
    half2v wv = tw[pos];
    float c1 = (float)wv.x, s1 = (float)wv.y;
    float c2 = c1 * c1 - s1 * s1, s2 = 2.f * c1 * s1;
    float c3 = c2 * c1 - s2 * s1, s3 = s2 * c1 + c2 * s1;
    float4 o0, o1, o2, o3;
    {
        float u1r = y1.x * c1 + y1.y * s1, u1i = y1.y * c1 - y1.x * s1;
        float u2r = y2.x * c2 + y2.y * s2, u2i = y2.y * c2 - y2.x * s2;
        float u3r = y3.x * c3 + y3.y * s3, u3i = y3.y * c3 - y3.x * s3;
        float s0r = y0.x + u2r, s0i = y0.y + u2i;
        float s1r = y0.x - u2r, s1i = y0.y - u2i;
        float s2r = u1r + u3r, s2i = u1i + u3i;
        float s3r = u1r - u3r, s3i = u1i - u3i;
        o0.x = s0r + s2r; o0.y = s0i + s2i;
        o2.x = s0r - s2r; o2.y = s0i - s2i;
        o1.x = s1r - s3i; o1.y = s1i + s3r;
        o3.x = s1r + s3i; o3.y = s1i - s3r;
    }
    {
        float u1r = y1.z * c1 + y1.w * s1, u1i = y1.w * c1 - y1.z * s1;
        float u2r = y2.z * c2 + y2.w * s2, u2i = y2.w * c2 - y2.z * s2;
        float u3r = y3.z * c3 + y3.w * s3, u3i = y3.w * c3 - y3.z * s3;
        float s0r = y0.z + u2r, s0i = y0.w + u2i;
        float s1r = y0.z - u2r, s1i = y0.w - u2i;
        float s2r = u1r + u3r, s2i = u1i + u3i;
        float s3r = u1r - u3r, s3i = u1i - u3i;
        o0.z = s0r + s2r; o0.w = s0i + s2i;
        o2.z = s0r - s2r; o2.w = s0i - s2i;
        o1.z = s1r - s3i; o1.w = s1i + s3r;
        o3.z = s1r + s3i; o3.w = s1i - s3r;
    }
    X[i0] = o0; X[i1] = o1; X[i2] = o2; X[i3] = o3;
}

__global__ __launch_bounds__(512) void k2_sfft(
        half2v* __restrict__ xf,
        const float* __restrict__ qr, const float* __restrict__ qi,
        const float* __restrict__ kr, const float* __restrict__ ki,
        const float* __restrict__ vr, const float* __restrict__ vi,
        const float* __restrict__ rtr, const float* __restrict__ rti) {
    __shared__ float4 buf[2304];
    __shared__ half2v twd[682];   // fwd twiddles: h=512@0, 128@512, 32@640, 8@672, 2@680
    int t = threadIdx.x;
    int g = blockIdx.x;
    int xcd = g & 7, r = g >> 3;
    int pp = xcd * 32 + (r & 31);
    int b = r >> 5;
    int p0 = pp * 2;
    half4v* colh = (half4v*)(xf + (size_t)b * 2048 * 512 + p0);

    // cooperative twiddle-table fill (2 passes over 512 threads)
    for (int i = t; i < 682; i += 512) {
        int h, off;
        if (i < 512)      { h = 512; off = 0; }
        else if (i < 640) { h = 128; off = 512; }
        else if (i < 672) { h = 32;  off = 640; }
        else if (i < 680) { h = 8;   off = 672; }
        else              { h = 2;   off = 680; }
        int pos = i - off;
        float s, c;
        __sincosf(-6.28318530717958647692f * (float)pos / (float)(4 * h), &s, &c);
        twd[i] = (half2v){(_Float16)c, (_Float16)s};
    }

#pragma unroll
    for (int c = 0; c < 4; c++) {
        int s = t + 512 * c;
        half4v h = colh[(size_t)s * 256];
        buf[pidx4(s)] = make_float4((float)h.x, (float)h.y, (float)h.z, (float)h.w);
    }
    __syncthreads(); r4_fwd(buf, t, 512, twd);
    __syncthreads(); r4_fwd(buf, t, 128, twd + 512);
    __syncthreads(); r4_fwd(buf, t, 32, twd + 640);
    __syncthreads(); r4_fwd(buf, t, 8, twd + 672);
    __syncthreads(); r4_fwd(buf, t, 2, twd + 680);
    __syncthreads();
#pragma unroll
    for (int c = 0; c < 2; c++) {
        int pr = t + 512 * c;
        int ia = pidx4(2 * pr), ib = pidx4(2 * pr + 1);
        float4 a = buf[ia], bb = buf[ib];
        buf[ia] = make_float4(a.x + bb.x, a.y + bb.y, a.z + bb.z, a.w + bb.w);
        buf[ib] = make_float4(a.x - bb.x, a.y - bb.y, a.z - bb.z, a.w - bb.w);
    }
    __syncthreads();

    int f0 = __brev((unsigned)p0) >> 23;
    int f1 = __brev((unsigned)(p0 + 1)) >> 23;
    float qw0r = qr[f0], qw0i = qi[f0], kw0r = kr[f0], kw0i = ki[f0], vw0r = vr[f0], vw0i = vi[f0];
    float qw1r = qr[f1], qw1i = qi[f1], kw1r = kr[f1], kw1i = ki[f1], vw1r = vr[f1], vw1i = vi[f1];
#pragma unroll
    for (int c = 0; c < 4; c++) {
        int idx = pidx4(t + 512 * c);
        float4 y = buf[idx];
        {
            float yr = y.x, yi = y.y;
            float qre = yr * qw0r - yi * qw0i, qim = yr * qw0i + yi * qw0r;
            float kre = yr * kw0r - yi * kw0i + 1e-12f, kim = yr * kw0i + yi * kw0r;
            float vre = yr * vw0r - yi * vw0i, vim = yr * vw0i + yi * vw0r;
            float inv = 1.0f / (kre * kre + kim * kim);
            float dre = (qre * kre + qim * kim) * inv;
            float dim = (qim * kre - qre * kim) * inv;
            y.x = dre * vre - dim * vim;
            y.y = dre * vim + dim * vre;
        }
        {
            float yr = y.z, yi = y.w;
            float qre = yr * qw1r - yi * qw1i, qim = yr * qw1i + yi * qw1r;
            float kre = yr * kw1r - yi * kw1i + 1e-12f, kim = yr * kw1i + yi * kw1r;
            float vre = yr * vw1r - yi * vw1i, vim = yr * vw1i + yi * vw1r;
            float inv = 1.0f / (kre * kre + kim * kim);
            float dre = (qre * kre + qim * kim) * inv;
            float dim = (qim * kre - qre * kim) * inv;
            y.z = dre * vre - dim * vim;
            y.w = dre * vim + dim * vre;
        }
        buf[idx] = y;
    }

    __syncthreads();
#pragma unroll
    for (int c = 0; c < 2; c++) {
        int pr = t + 512 * c;
        int ia = pidx4(2 * pr), ib = pidx4(2 * pr + 1);
        float4 a = buf[ia], bb = buf[ib];
        buf[ia] = make_float4(a.x + bb.x, a.y + bb.y, a.z + bb.z, a.w + bb.w);
        buf[ib] = make_float4(a.x - bb.x, a.y - bb.y, a.z - bb.z, a.w - bb.w);
    }
    __syncthreads(); r4_inv(buf, t, 2, twd + 680);
    __syncthreads(); r4_inv(buf, t, 8, twd + 672);
    __syncthreads(); r4_inv(buf, t, 32, twd + 640);
    __syncthreads(); r4_inv(buf, t, 128, twd + 512);
    __syncthreads(); r4_inv(buf, t, 512, twd);
    __syncthreads();

    const float sc = 1.0f / 2048.0f;
    float r0r = rtr[f0] * sc, r0i = rti[f0] * sc;
    float r1r = rtr[f1] * sc, r1i = rti[f1] * sc;
#pragma unroll
    for (int c = 0; c < 4; c++) {
        int s = t + 512 * c;
        float4 z = buf[pidx4(s)];
        float ox = z.x * r0r - z.y * r0i, oy = z.x * r0i + z.y * r0r;
        float oz = z.z * r1r - z.w * r1i, ow = z.z * r1i + z.w * r1r;
        colh[(size_t)s * 256] = (half4v){(_Float16)ox, (_Float16)oy, (_Float16)oz, (_Float16)ow};
    }
}

// ---------------- k3 : row-pair residual + dyt_b + q/k (Parseval-packed) + v ----------------
__global__ __launch_bounds__(256) void k3_mid(
        const half2v* __restrict__ xf,
        const float* __restrict__ x,
        const float* __restrict__ alpha, const float* __restrict__ w, const float* __restrict__ bia,
        const float* __restrict__ qr, const float* __restrict__ qi,
        const float* __restrict__ kr, const float* __restrict__ ki,
        const float* __restrict__ vr, const float* __restrict__ vi,
        float* __restrict__ x1,
        unsigned short* __restrict__ qb, unsigned short* __restrict__ kb, unsigned short* __restrict__ vb) {
    __shared__ __align__(16) char smem[4 * 1024 * 8];  // 32KB
    int tid = threadIdx.x, lane = tid & 63, wv = tid >> 6;
    float2* zb = (float2*)(smem + wv * 8192);          // phase1: wave-private 8KB
    float* wbs = (float*)smem;                          // [6][512]=12KB (after combine)
    float2* zf = (float2*)(smem + 12288 + wv * 4096);  // phase2: wave-private 4KB
    size_t pr = (size_t)blockIdx.x * 4 + wv;
    size_t r1 = pr * 2, r2 = r1 + 1;
    float tc[12], ts[12];
    wtw512(tc, ts, lane);

    float xa[8], xb2[8];
#pragma unroll
    for (int j = 0; j < 8; j++) {
        int d = j * 64 + lane;
        half2v h1 = xf[r1 * 512 + d];
        half2v h2 = xf[r2 * 512 + d];
        zb[d]       = make_float2((float)h1.x, (float)h1.y);
        zb[512 + d] = make_float2((float)h2.x, (float)h2.y);
        xa[j]  = x[r1 * 512 + d];
        xb2[j] = x[r2 * 512 + d];
    }
    float re[8], im[8];
#pragma unroll
    for (int j = 0; j < 8; j++) {
        int d = j * 64 + lane;
        int fd = __brev((unsigned)d) >> 23;
        int dp = __brev((unsigned)((512 - fd) & 511)) >> 23;
        float2 z1 = zb[d], z1p = zb[dp];
        float2 z2 = zb[512 + d], z2p = zb[512 + dp];
        float h1r = 0.5f * (z1.x + z1p.x), h1i = 0.5f * (z1.y - z1p.y);
        float h2r = 0.5f * (z2.x + z2p.x), h2i = 0.5f * (z2.y - z2p.y);
        re[j] = h1r - h2i;
        im[j] = h1i + h2r;
    }
    __syncthreads();
    for (int idx = tid; idx < 512; idx += 256) {
        int f = __brev((unsigned)idx) >> 23;
        int gg = (512 - f) & 511;
        float aa = (f == 0 || f == 256) ? 0.04419417382415922f : 0.0625f;
        float ah = aa * 0.5f;
        const float s5 = 0.5f * (1.0f / 512.0f);
        wbs[0 * 512 + idx] = ah * (qr[f] + qr[gg]); wbs[1 * 512 + idx] = ah * (qi[f] - qi[gg]);
        wbs[2 * 512 + idx] = ah * (kr[f] + kr[gg]); wbs[3 * 512 + idx] = ah * (ki[f] - ki[gg]);
        wbs[4 * 512 + idx] = s5 * (vr[f] + vr[gg]); wbs[5 * 512 + idx] = s5 * (vi[f] - vi[gg]);
    }

    wfft512<true>(re, im, tc, ts, lane);
    float a = alpha[0];
    float gre[8], gim[8];
#pragma unroll
    for (int j = 0; j < 8; j++) {
        int d = j * 64 + lane;
        float v1 = re[j] * (1.0f / 512.0f) + xa[j];
        float v2 = im[j] * (1.0f / 512.0f) + xb2[j];
        x1[r1 * 512 + d] = v1;
        x1[r2 * 512 + d] = v2;
        gre[j] = dyt_tanh(a * v1) * w[d] + bia[d];
        gim[j] = dyt_tanh(a * v2) * w[d] + bia[d];
    }
    wfft512<false>(gre, gim, tc, ts, lane);
    __syncthreads();

#pragma unroll
    for (int j = 0; j < 8; j++)
        zf[j * 64 + lane] = make_float2(gre[j], gim[j]);

    float pvr[8], pvi[8];
#pragma unroll
    for (int j = 0; j < 8; j++) {
        int i = j * 64 + lane;
        float wr0 = wbs[4 * 512 + i], wi0 = wbs[5 * 512 + i];
        pvr[j] = gre[j] * wr0 - gim[j] * wi0;
        pvi[j] = gre[j] * wi0 + gim[j] * wr0;
    }

    bool odd = (lane & 1) != 0;
#pragma unroll
    for (int j = 0; j < 8; j++) {
        int d = j * 64 + lane;
        int fd = __brev((unsigned)d) >> 23;
        int dp = __brev((unsigned)((512 - fd) & 511)) >> 23;
        float2 Zp = zf[dp];
        float zr = gre[j], zi = gim[j];
        float A1r = 0.5f * (zr + Zp.x), A1i = 0.5f * (zi - Zp.y);
        float A2r = 0.5f * (zi + Zp.y), A2i = 0.5f * (Zp.x - zr);
        float wr0 = wbs[0 * 512 + d], wi0 = wbs[1 * 512 + d];
        float Q1r = A1r * wr0 - A1i * wi0, Q1i = A1r * wi0 + A1i * wr0;
        float Q2r = A2r * wr0 - A2i * wi0, Q2i = A2r * wi0 + A2i * wr0;
        qb[r1 * 512 + d] = f2bf(odd ? -Q1i : Q1r);
        qb[r2 * 512 + d] = f2bf(odd ? -Q2i : Q2r);
        float wr1 = wbs[2 * 512 + d], wi1 = wbs[3 * 512 + d];
        float K1r = A1r * wr1 - A1i * wi1, K1i = A1r * wi1 + A1i * wr1;
        float K2r = A2r * wr1 - A2i * wi1, K2i = A2r * wi1 + A2i * wr1;
        kb[r1 * 512 + d] = f2bf(odd ? -K1i : K1r);
        kb[r2 * 512 + d] = f2bf(odd ? -K2i : K2r);
    }

    wfft512<true>(pvr, pvi, tc, ts, lane);
#pragma unroll
    for (int j = 0; j < 8; j++) {
        int d = j * 64 + lane;
        vb[r1 * 512 + d] = f2bf(pvr[j]);
        vb[r2 * 512 + d] = f2bf(pvi[j]);
    }
}

// ---------------- unified bt-GEMM (BK=64, global_load_lds, XOR-swizzled LDS) ----------------
__global__ __launch_bounds__(256) void gemm_bt(
        const unsigned short* __restrict__ A, const unsigned short* __restrict__ Bt,
        void* __restrict__ C, int M, int N, int Ks, int kseg, float scale, int out_half) {
    int tilesM = M >> 7, tilesN = N >> 7;
    int perBatch = tilesM * tilesN;
    int l = blockIdx.x;
    int seg = blockIdx.y;
    int s = l & 7, t = l >> 3;
    int cnt = perBatch >> 3;
    int bz = t / cnt;
    int u = t - bz * cnt;
    int pn = tilesN >> 1, pm = tilesM >> 2;
    int n0 = ((s & 1) * pn + (u % pn)) << 7;
    int m0 = ((s >> 1) * pm + (u / pn)) << 7;
    int kbase = seg * kseg;

    const unsigned short* Ab = A + (size_t)bz * M * Ks;
    const unsigned short* Bb = Bt + (size_t)bz * N * Ks;
    __shared__ __align__(16) unsigned short smem[2 * 128 * 64];
    unsigned short* As = smem;
    unsigned short* Bs = smem + 128 * 64;
    int tid = threadIdx.x;
    int wave = tid >> 6, lane = tid & 63;
    int wm = (wave >> 1) * 64, wn = (wave & 1) * 64;
    int lrow = lane & 15, lq = lane >> 4;
    floatx4 acc[4][4];
#pragma unroll
    for (int i = 0; i < 4; i++)
#pragma unroll
        for (int j = 0; j < 4; j++)
            acc[i][j] = (floatx4){0.f, 0.f, 0.f, 0.f};

    int lr = lane >> 3;
    int lcs = lane & 7;
    for (int k0 = kbase; k0 < kbase + kseg; k0 += 64) {
        __syncthreads();
#pragma unroll
        for (int i = 0; i < 4; i++) {
            int c = wave * 4 + i;
            int r = c * 8 + lr;
            int gcol = ((lcs ^ (r & 7)) << 3);
            async_load16(Ab + (size_t)(m0 + r) * Ks + k0 + gcol, As + c * 512);
            async_load16(Bb + (size_t)(n0 + r) * Ks + k0 + gcol, Bs + c * 512);
        }
        __syncthreads();
        bf16x8 a0[4], a1[4], b0[4], b1[4];
#pragma unroll
        for (int mi = 0; mi < 4; mi++) {
            int r = wm + mi * 16 + lrow;
            a0[mi] = *(const bf16x8*)(As + r * 64 + ((lq ^ (r & 7)) << 3));
            a1[mi] = *(const bf16x8*)(As + r * 64 + (((lq + 4) ^ (r & 7)) << 3));
        }
#pragma unroll
        for (int ni = 0; ni < 4; ni++) {
            int r = wn + ni * 16 + lrow;
            b0[ni] = *(const bf16x8*)(Bs + r * 64 + ((lq ^ (r & 7)) << 3));
            b1[ni] = *(const bf16x8*)(Bs + r * 64 + (((lq + 4) ^ (r & 7)) << 3));
        }
#pragma unroll
        for (int mi = 0; mi < 4; mi++)
#pragma unroll
            for (int ni = 0; ni < 4; ni++) {
                acc[mi][ni] = __builtin_amdgcn_mfma_f32_16x16x32_bf16(a0[mi], b0[ni], acc[mi][ni], 0, 0, 0);
                acc[mi][ni] = __builtin_amdgcn_mfma_f32_16x16x32_bf16(a1[mi], b1[ni], acc[mi][ni], 0, 0, 0);
            }
    }
    size_t cbase = ((size_t)seg * 4 + bz) * (size_t)M * N;
    int lr0 = (wave >> 1) * 16 + lq * 4;
    for (int mi = 0; mi < 4; mi++) {
        __syncthreads();
        if (out_half) {
            _Float16* Cs = (_Float16*)smem;
            for (int ni = 0; ni < 4; ni++)
                for (int r = 0; r < 4; r++)
                    Cs[(lr0 + r) * 128 + wn + ni * 16 + lrow] = (_Float16)(acc[mi][ni][r] * scale);
            __syncthreads();
            for (int h = 0; h < 2; h++) {
                int chunk = tid + h * 256;
                int rl = chunk >> 4, cb = (chunk & 15) * 16;
                int grow = m0 + mi * 16 + (rl & 15) + (rl >> 4) * 64;
                *(uint4*)((char*)C + (cbase + (size_t)grow * N + n0) * 2 + cb) =
                    *(const uint4*)((const char*)Cs + rl * 256 + cb);
            }
        } else {
            float* Cs = (float*)smem;
            for (int ni = 0; ni < 4; ni++)
                for (int r = 0; r < 4; r++)
                    Cs[(lr0 + r) * 128 + wn + ni * 16 + lrow] = acc[mi][ni][r] * scale;
            __syncthreads();
            for (int h = 0; h < 4; h++) {
                int chunk = tid + h * 256;
                int rl = chunk >> 5, cb = (chunk & 31) * 16;
                int grow = m0 + mi * 16 + (rl & 15) + (rl >> 4) * 64;
                *(uint4*)((char*)C + (cbase + (size_t)grow * N + n0) * 4 + cb) =
                    *(const uint4*)((const char*)Cs + rl * 512 + cb);
            }
        }
    }
}

// ---------------- softmax (in-place bf16 P) + v->vT transpose, one grid ----------------
__global__ __launch_bounds__(256) void sm_tr(
        const _Float16* __restrict__ Sc, unsigned short* __restrict__ P,
        const unsigned short* __restrict__ vb, unsigned short* __restrict__ vT) {
    __shared__ __align__(16) char lds[64 * 65 * 2];  // transpose tile; softmax uses first 16B
    if (blockIdx.x < 8192) {
        float* red = (float*)lds;
        int tid = threadIdx.x;
        size_t row = blockIdx.x;
        halfx8 hv = *(const halfx8*)(Sc + row * 2048 + tid * 8);
        float v[8];
#pragma unroll
        for (int j = 0; j < 8; j++) v[j] = (float)hv[j];
        float mx = v[0];
#pragma unroll
        for (int j = 1; j < 8; j++) mx = fmaxf(mx, v[j]);
        for (int off = 32; off >= 1; off >>= 1) mx = fmaxf(mx, __shfl_xor(mx, off));
        int wv = tid >> 6;
        if ((tid & 63) == 0) red[wv] = mx;
        __syncthreads();
        mx = fmaxf(fmaxf(red[0], red[1]), fmaxf(red[2], red[3]));
        float e[8], sum = 0.f;
#pragma unroll
        for (int j = 0; j < 8; j++) { e[j] = __expf(v[j] - mx); sum += e[j]; }
        for (int off = 32; off >= 1; off >>= 1) sum += __shfl_xor(sum, off);
        __syncthreads();
        if ((tid & 63) == 0) red[wv] = sum;
        __syncthreads();
        float inv = 1.0f / (red[0] + red[1] + red[2] + red[3]);
        ushortx8 o;
#pragma unroll
        for (int j = 0; j < 8; j++) o[j] = f2bf(e[j] * inv);
        *(ushortx8*)(P + row * 2048 + tid * 8) = o;
    } else {
        unsigned short (*tile)[65] = (unsigned short (*)[65])lds;
        int id = blockIdx.x - 8192;           // 1024 transpose blocks: (32, 8, 4)
        int sx = id & 31, dy = (id >> 5) & 7, bz = id >> 8;
        int s0 = sx * 64, d0 = dy * 64;
        int tx = threadIdx.x & 63, ty = threadIdx.x >> 6;
        for (int j = 0; j < 16; j++) {
            int s = ty + j * 4;
            tile[s][tx] = vb[((size_t)bz * 2048 + s0 + s) * 512 + d0 + tx];
        }
        __syncthreads();
        for (int j = 0; j < 16; j++) {
            int d = ty + j * 4;
            vT[((size_t)bz * 512 + d0 + d) * 2048 + s0 + tx] = tile[tx][d];
        }
    }
}

// ---------------- k5 : row-pair residual + dyt_f + spectral filter ----------------
// R23: sums TWO fp16 split-K partials.
__global__ __launch_bounds__(256) void k5_ffn(
        const _Float16* __restrict__ attn0, const _Float16* __restrict__ attn1,
        const float* __restrict__ x1,
        const float* __restrict__ alpha, const float* __restrict__ w, const float* __restrict__ bia,
        const float* __restrict__ br, const float* __restrict__ bi,
        float* __restrict__ out) {
    __shared__ float wbs[2][512];
    int tid = threadIdx.x, lane = tid & 63, wv = tid >> 6;
    size_t pr = (size_t)blockIdx.x * 4 + wv;
    size_t r1 = pr * 2, r2 = r1 + 1;
    for (int idx = tid; idx < 512; idx += 256) {
        int f = __brev((unsigned)idx) >> 23;
        int gg = (512 - f) & 511;
        wbs[0][idx] = 0.5f * (br[f] + br[gg]) * (1.0f / 512.0f);
        wbs[1][idx] = 0.5f * (bi[f] - bi[gg]) * (1.0f / 512.0f);
    }
    float tc[12], ts[12];
    wtw512(tc, ts, lane);
    float a = alpha[0];
    float re[8], im[8], x2a[8], x2b[8];
#pragma unroll
    for (int j = 0; j < 8; j++) {
        int d = j * 64 + lane;
        float v1 = (float)attn0[r1 * 512 + d] + (float)attn1[r1 * 512 + d] + x1[r1 * 512 + d];
        float v2 = (float)attn0[r2 * 512 + d] + (float)attn1[r2 * 512 + d] + x1[r2 * 512 + d];
        x2a[j] = v1; x2b[j] = v2;
        re[j] = dyt_tanh(a * v1) * w[d] + bia[d];
        im[j] = dyt_tanh(a * v2) * w[d] + bia[d];
    }
    wfft512<false>(re, im, tc, ts, lane);
    __syncthreads();
#pragma unroll
    for (int j = 0; j < 8; j++) {
        int i = j * 64 + lane;
        float wr0 = wbs[0][i], wi0 = wbs[1][i];
        float rr = re[j], ii = im[j];
        re[j] = rr * wr0 - ii * wi0;
        im[j] = rr * wi0 + ii * wr0;
    }
    wfft512<true>(re, im, tc, ts, lane);
#pragma unroll
    for (int j = 0; j < 8; j++) {
        int d = j * 64 + lane;
        out[r1 * 512 + d] = re[j] + x2a[j];
        out[r2 * 512 + d] = im[j] + x2b[j];
    }
}

extern "C" void kernel_launch(void* const* d_in, const int* in_sizes, int n_in,
                              void* d_out, int out_size, void* d_ws, size_t ws_size,
                              hipStream_t stream) {
    const float* x      = (const float*)d_in[0];
    const float* a_qr   = (const float*)d_in[1];
    const float* a_kr   = (const float*)d_in[2];
    const float* a_vr   = (const float*)d_in[3];
    const float* a_rtr  = (const float*)d_in[4];
    const float* b_qr   = (const float*)d_in[5];
    const float* b_kr   = (const float*)d_in[6];
    const float* b_vr   = (const float*)d_in[7];
    /* f_ar = d_in[8] unused (dead gelu branch) */
    const float* f_br   = (const float*)d_in[9];
    const float* a_qi   = (const float*)d_in[10];
    const float* a_ki   = (const float*)d_in[11];
    const float* a_vi   = (const float*)d_in[12];
    const float* a_rti  = (const float*)d_in[13];
    const float* b_qi   = (const float*)d_in[14];
    const float* b_ki   = (const float*)d_in[15];
    const float* b_vi   = (const float*)d_in[16];
    /* f_ai = d_in[17] unused */
    const float* f_bi   = (const float*)d_in[18];
    /* f_bias = d_in[19] unused (dead gelu branch) */
    const float* dyta_alpha = (const float*)d_in[20];
    const float* dyta_w     = (const float*)d_in[21];
    const float* dyta_b     = (const float*)d_in[22];
    const float* dytb_alpha = (const float*)d_in[23];
    const float* dytb_w     = (const float*)d_in[24];
    const float* dytb_b     = (const float*)d_in[25];
    const float* dytf_alpha = (const float*)d_in[26];
    const float* dytf_w     = (const float*)d_in[27];
    const float* dytf_b     = (const float*)d_in[28];
    (void)in_sizes; (void)n_in; (void)out_size; (void)ws_size;

    char* ws = (char*)d_ws;
    const size_t MB = 1024 * 1024;
    half2v* xfH = (half2v*)(ws + 0 * MB);           // 16MB packed fp16 complex
    float* x1   = (float*)(ws + 32 * MB);           // 16MB
    unsigned short* qb = (unsigned short*)(ws + 48 * MB);  // 8MB
    unsigned short* kb = (unsigned short*)(ws + 56 * MB);  // 8MB
    unsigned short* vb = (unsigned short*)(ws + 64 * MB);  // 8MB
    unsigned short* vT = (unsigned short*)(ws + 72 * MB);  // 8MB
    _Float16* scores   = (_Float16*)(ws + 0 * MB);  // 32MB, overlays dead xfH
    unsigned short* Pb = (unsigned short*)(ws + 0 * MB);   // bf16 P, in place over scores
    _Float16* attnP    = (_Float16*)(ws + 81 * MB); // 16MB: two 8MB fp16 K-split partials
    float* outp = (float*)d_out;

    k1_dyt_fftd<<<2048, 256, 0, stream>>>(x, dyta_alpha, dyta_w, dyta_b, xfH);
    k2_sfft<<<1024, 512, 0, stream>>>(xfH, a_qr, a_qi, a_kr, a_ki, a_vr, a_vi, a_rtr, a_rti);
    k3_mid<<<1024, 256, 0, stream>>>(xfH, x, dytb_alpha, dytb_w, dytb_b,
                                     b_qr, b_qi, b_kr, b_ki, b_vr, b_vi, x1, qb, kb, vb);
    gemm_bt<<<1024, 256, 0, stream>>>(qb, kb, scores, 2048, 2048, 512, 512,
                                      0.04419417382415922f, 1);
    sm_tr<<<9216, 256, 0, stream>>>(scores, Pb, vb, vT);
    gemm_bt<<<dim3(256, 2), 256, 0, stream>>>(Pb, vT, attnP, 2048, 512, 2048, 1024,
                                              1.0f, 1);
    k5_ffn<<<1024, 256, 0, stream>>>(attnP, attnP + (size_t)4 * 2048 * 512, x1,
                                     dytf_alpha, dytf_w, dytf_b, f_br, f_bi, outp);
}

// Round 7
// 281.932 us; speedup vs baseline: 1.0392x; 1.0026x over previous
//
#include <hip/hip_runtime.h>

// B=4, S=2048, D=512, fp32 in/out. threshold 1.45e-1.
// Pipeline (Hermitian-packed D-FFTs: one 512-pt FFT serves TWO rows):
//  k1 : u=dyt_a(x); XfH = FFT_D(u)          (wave-register FFT, bitrev bins, half2 storage)
//  k2 : per column-PAIR: in-place radix-4 2048-pt S-FFT (fp32 LDS, fp16 global),
//       spectral op, exact inverse, *rtw/S. Twiddles from a 682-entry LDS table.
//  k3 : per ROW-PAIR: Hermitian combine, x1, dyt_b; q,k Parseval-packed in the
//       frequency domain (no inverse FFTs); v packed inverse FFT.
//  g1 : scores = q@k^T
//  smtr: full softmax per row written in place as bf16 P + v->vT transpose.
//  g2 : attn = P@vT, split-K x2, fp16 partials.
//  k5 : row-pair packed dyt_f + spectral filter (sums TWO fp16 partials)
// R24: k1/k3/k5 get __launch_bounds__(256, 4). Diagnosis: k3 showed
// VGPR_Count=64 but ~72-80 live floats (tc/ts[24] live whole kernel + gre/gim
// + pvr/pvi + combine temps) -> compiler spills to scratch under the default
// 8-waves/EU budget; every reload sits on the serial FFT chain (explains 94%
// per-wave stall, VALUBusy 25%, HBM 12%). Grid caps these kernels at 4
// waves/SIMD anyway (4096 waves total), so min-waves=4 raises the VGPR cap
// to 128 at ZERO occupancy cost. k2/gemm/sm_tr untouched (isolation).

typedef __attribute__((ext_vector_type(8))) __bf16 bf16x8;
typedef __attribute__((ext_vector_type(4))) float floatx4;
typedef __attribute__((ext_vector_type(8))) _Float16 halfx8;
typedef __attribute__((ext_vector_type(8))) unsigned short ushortx8;
typedef __attribute__((ext_vector_type(2))) _Float16 half2v;   // 4B packed complex (re,im)
typedef __attribute__((ext_vector_type(4))) _Float16 half4v;   // 8B = two packed complex

__device__ __forceinline__ unsigned short f2bf(float x) {
    unsigned u = __float_as_uint(x);
    u = (u + 0x7fffu + ((u >> 16) & 1u)) >> 16;
    return (unsigned short)u;
}

__device__ __forceinline__ float dyt_tanh(float x) {
    float e = __expf(2.0f * x);
    return 1.0f - 2.0f / (e + 1.0f);
}

__device__ __forceinline__ void async_load16(const unsigned short* g, unsigned short* l) {
    __builtin_amdgcn_global_load_lds(
        (const __attribute__((address_space(1))) unsigned int*)g,
        (__attribute__((address_space(3))) unsigned int*)l, 16, 0, 0);
}

// ---------- wave-level 512-pt FFT (8 pts/lane) ----------
__device__ __forceinline__ void wtw512(float (&tc)[12], float (&ts)[12], int lane) {
    const float w = -6.28318530717958647692f / 512.0f;
#pragma unroll
    for (int j = 0; j < 4; j++) __sincosf(w * (float)(j * 64 + lane), &ts[j], &tc[j]);
#pragma unroll
    for (int j = 0; j < 2; j++) __sincosf(w * (float)(2 * (j * 64 + lane)), &ts[4 + j], &tc[4 + j]);
    __sincosf(w * (float)(4 * lane), &ts[6], &tc[6]);
    __sincosf(w * (float)(8 * (lane & 31)), &ts[7], &tc[7]);
    __sincosf(w * (float)(16 * (lane & 15)), &ts[8], &tc[8]);
    __sincosf(w * (float)(32 * (lane & 7)), &ts[9], &tc[9]);
    __sincosf(w * (float)(64 * (lane & 3)), &ts[10], &tc[10]);
    __sincosf(w * (float)(128 * (lane & 1)), &ts[11], &tc[11]);
}

template <bool INV>
__device__ __forceinline__ void wfft512(float (&re)[8], float (&im)[8],
                                        const float (&tc)[12], const float (&ts)[12], int lane) {
    if (!INV) {
#pragma unroll
        for (int j = 0; j < 4; j++) {
            float ur = re[j], ui = im[j], vr = re[j + 4], vi = im[j + 4];
            re[j] = ur + vr; im[j] = ui + vi;
            float dr = ur - vr, di = ui - vi;
            re[j + 4] = dr * tc[j] - di * ts[j];
            im[j + 4] = dr * ts[j] + di * tc[j];
        }
#pragma unroll
        for (int g = 0; g < 8; g += 4)
#pragma unroll
            for (int jj = 0; jj < 2; jj++) {
                int j = g + jj;
                float ur = re[j], ui = im[j], vr = re[j + 2], vi = im[j + 2];
                re[j] = ur + vr; im[j] = ui + vi;
                float dr = ur - vr, di = ui - vi;
                re[j + 2] = dr * tc[4 + jj] - di * ts[4 + jj];
                im[j + 2] = dr * ts[4 + jj] + di * tc[4 + jj];
            }
#pragma unroll
        for (int j = 0; j < 8; j += 2) {
            float ur = re[j], ui = im[j], vr = re[j + 1], vi = im[j + 1];
            re[j] = ur + vr; im[j] = ui + vi;
            float dr = ur - vr, di = ui - vi;
            re[j + 1] = dr * tc[6] - di * ts[6];
            im[j + 1] = dr * ts[6] + di * tc[6];
        }
#pragma unroll
        for (int st = 0; st < 6; st++) {
            int h = 32 >> st;
            bool hi = (lane & h) != 0;
            float c = (st < 5) ? tc[7 + st] : 1.0f;
            float s = (st < 5) ? ts[7 + st] : 0.0f;
#pragma unroll
            for (int j = 0; j < 8; j++) {
                float orr = __shfl_xor(re[j], h, 64);
                float oii = __shfl_xor(im[j], h, 64);
                float dr = orr - re[j], di = oii - im[j];
                float sr = re[j] + orr, si = im[j] + oii;
                re[j] = hi ? (dr * c - di * s) : sr;
                im[j] = hi ? (dr * s + di * c) : si;
            }
        }
    } else {
#pragma unroll
        for (int st = 5; st >= 0; st--) {
            int h = 32 >> st;
            bool hi = (lane & h) != 0;
            float c = (st < 5) ? tc[7 + st] : 1.0f;
            float s = (st < 5) ? ts[7 + st] : 0.0f;
#pragma unroll
            for (int j = 0; j < 8; j++) {
                float zr = re[j], zi = im[j];
                float vr = zr * c + zi * s;
                float vi = zi * c - zr * s;
                float mr = hi ? vr : zr;
                float mi = hi ? vi : zi;
                float orr = __shfl_xor(mr, h, 64);
                float oii = __shfl_xor(mi, h, 64);
                re[j] = hi ? (orr - vr) : (zr + orr);
                im[j] = hi ? (oii - vi) : (zi + oii);
            }
        }
#pragma unroll
        for (int j = 0; j < 8; j += 2) {
            float vr = re[j + 1] * tc[6] + im[j + 1] * ts[6];
            float vi = im[j + 1] * tc[6] - re[j + 1] * ts[6];
            re[j + 1] = re[j] - vr; im[j + 1] = im[j] - vi;
            re[j] += vr; im[j] += vi;
        }
#pragma unroll
        for (int g = 0; g < 8; g += 4)
#pragma unroll
            for (int jj = 0; jj < 2; jj++) {
                int j = g + jj;
                float vr = re[j + 2] * tc[4 + jj] + im[j + 2] * ts[4 + jj];
                float vi = im[j + 2] * tc[4 + jj] - re[j + 2] * ts[4 + jj];
                re[j + 2] = re[j] - vr; im[j + 2] = im[j] - vi;
                re[j] += vr; im[j] += vi;
            }
#pragma unroll
        for (int j = 0; j < 4; j++) {
            float vr = re[j + 4] * tc[j] + im[j + 4] * ts[j];
            float vi = im[j + 4] * tc[j] - re[j + 4] * ts[j];
            re[j + 4] = re[j] - vr; im[j + 4] = im[j] - vi;
            re[j] += vr; im[j] += vi;
        }
    }
}

// ---------------- k1 : dyt_a + forward D-FFT (half2 output) ----------------
__global__ __launch_bounds__(256, 4) void k1_dyt_fftd(
        const float* __restrict__ x,
        const float* __restrict__ alpha, const float* __restrict__ w, const float* __restrict__ bia,
        half2v* __restrict__ xf) {
    int tid = threadIdx.x, lane = tid & 63, wv = tid >> 6;
    size_t row = (size_t)blockIdx.x * 4 + wv;
    float tc[12], ts[12];
    wtw512(tc, ts, lane);
    float re[8], im[8];
    float a = alpha[0];
    const float* xr = x + row * 512;
#pragma unroll
    for (int j = 0; j < 8; j++) {
        int d = j * 64 + lane;
        re[j] = dyt_tanh(a * xr[d]) * w[d] + bia[d];
        im[j] = 0.f;
    }
    wfft512<false>(re, im, tc, ts, lane);
#pragma unroll
    for (int j = 0; j < 8; j++) {
        int d = j * 64 + lane;
        xf[row * 512 + d] = (half2v){(_Float16)re[j], (_Float16)im[j]};
    }
}

// ---------------- k2 : in-place radix-4 2048-pt S-FFT, 2 cols/block ----------------
__device__ __forceinline__ int pidx4(int i) { return i + (i >> 3); }

// Both fwd and inv read the SAME table entry (c,s) = sincos(-2*pi*pos/(4h));
// inv applies the conjugate internally (u = y*(c - i*s)).
__device__ __forceinline__ void r4_fwd(float4* X, int t, int h, const half2v* tw) {
    int pos = t & (h - 1);
    int i = ((t & ~(h - 1)) << 2) | pos;
    int i0 = pidx4(i), i1 = pidx4(i + h), i2 = pidx4(i + 2 * h), i3 = pidx4(i + 3 * h);
    float4 a0 = X[i0], a1 = X[i1], a2 = X[i2], a3 = X[i3];
    half2v wv = tw[pos];
    float c1 = (float)wv.x, s1 = (float)wv.y;
    float c2 = c1 * c1 - s1 * s1, s2 = 2.f * c1 * s1;
    float c3 = c2 * c1 - s2 * s1, s3 = s2 * c1 + c2 * s1;
    float4 o0, o1, o2, o3;
    {
        float t0r = a0.x + a2.x, t0i = a0.y + a2.y, t1r = a0.x - a2.x, t1i = a0.y - a2.y;
        float t2r = a1.x + a3.x, t2i = a1.y + a3.y, t3r = a1.x - a3.x, t3i = a1.y - a3.y;
        o0.x = t0r + t2r; o0.y = t0i + t2i;
        float b1r = t1r + t3i, b1i = t1i - t3r;
        float b2r = t0r - t2r, b2i = t0i - t2i;
        float b3r = t1r - t3i, b3i = t1i + t3r;
        o1.x = b1r * c1 - b1i * s1; o1.y = b1r * s1 + b1i * c1;
        o2.x = b2r * c2 - b2i * s2; o2.y = b2r * s2 + b2i * c2;
        o3.x = b3r * c3 - b3i * s3; o3.y = b3r * s3 + b3i * c3;
    }
    {
        float t0r = a0.z + a2.z, t0i = a0.w + a2.w, t1r = a0.z - a2.z, t1i = a0.w - a2.w;
        float t2r = a1.z + a3.z, t2i = a1.w + a3.w, t3r = a1.z - a3.z, t3i = a1.w - a3.w;
        o0.z = t0r + t2r; o0.w = t0i + t2i;
        float b1r = t1r + t3i, b1i = t1i - t3r;
        float b2r = t0r - t2r, b2i = t0i - t2i;
        float b3r = t1r - t3i, b3i = t1i + t3r;
        o1.z = b1r * c1 - b1i * s1; o1.w = b1r * s1 + b1i * c1;
        o2.z = b2r * c2 - b2i * s2; o2.w = b2r * s2 + b2i * c2;
        o3.z = b3r * c3 - b3i * s3; o3.w = b3r * s3 + b3i * c3;
    }
    X[i0] = o0; X[i1] = o1; X[i2] = o2; X[i3] = o3;
}

__device__ __forceinline__ void r4_inv(float4* X, int t, int h, const half2v* tw) {
    int pos = t & (h - 1);
    int i = ((t & ~(h - 1)) << 2) | pos;
    int i0 = pidx4(i), i1 = pidx4(i + h), i2 = pidx4(i + 2 * h), i3 = pidx4(i + 3 * h);
    float4 y0 = X[i0], y1 = X[i1], y2 = X[i2], y3 = X[i3];
    half2v wv = tw[pos];
    float c1 = (float)wv.x, s1 = (float)wv.y;
    float c2 = c1 * c1 - s1 * s1, s2 = 2.f * c1 * s1;
    float c3 = c2 * c1 - s2 * s1, s3 = s2 * c1 + c2 * s1;
    float4 o0, o1, o2, o3;
    {
        float u1r = y1.x * c1 + y1.y * s1, u1i = y1.y * c1 - y1.x * s1;
        float u2r = y2.x * c2 + y2.y * s2, u2i = y2.y * c2 - y2.x * s2;
        float u3r = y3.x * c3 + y3.y * s3, u3i = y3.y * c3 - y3.x * s3;
        float s0r = y0.x + u2r, s0i = y0.y + u2i;
        float s1r = y0.x - u2r, s1i = y0.y - u2i;
        float s2r = u1r + u3r, s2i = u1i + u3i;
        float s3r = u1r - u3r, s3i = u1i - u3i;
        o0.x = s0r + s2r; o0.y = s0i + s2i;
        o2.x = s0r - s2r; o2.y = s0i - s2i;
        o1.x = s1r - s3i; o1.y = s1i + s3r;
        o3.x = s1r + s3i; o3.y = s1i - s3r;
    }
    {
        float u1r = y1.z * c1 + y1.w * s1, u1i = y1.w * c1 - y1.z * s1;
        float u2r = y2.z * c2 + y2.w * s2, u2i = y2.w * c2 - y2.z * s2;
        float u3r = y3.z * c3 + y3.w * s3, u3i = y3.w * c3 - y3.z * s3;
        float s0r = y0.z + u2r, s0i = y0.w + u2i;
        float s1r = y0.z - u2r, s1i = y0.w - u2i;
        float s2r = u1r + u3r, s2i = u1i + u3i;
        float s3r = u1r - u3r, s3i = u1i - u3i;
        o0.z = s0r + s2r; o0.w = s0i + s2i;
        o2.z = s0r - s2r; o2.w = s0i - s2i;
        o1.z = s1r - s3i; o1.w = s1i + s3r;
        o3.z = s1r + s3i; o3.w = s1i - s3r;
    }
    X[i0] = o0; X[i1] = o1; X[i2] = o2; X[i3] = o3;
}

__global__ __launch_bounds__(512) void k2_sfft(
        half2v* __restrict__ xf,
        const float* __restrict__ qr, const float* __restrict__ qi,
        const float* __restrict__ kr, const float* __restrict__ ki,
        const float* __restrict__ vr, const float* __restrict__ vi,
        const float* __restrict__ rtr, const float* __restrict__ rti) {
    __shared__ float4 buf[2304];
    __shared__ half2v twd[682];   // fwd twiddles: h=512@0, 128@512, 32@640, 8@672, 2@680
    int t = threadIdx.x;
    int g = blockIdx.x;
    int xcd = g & 7, r = g >> 3;
    int pp = xcd * 32 + (r & 31);
    int b = r >> 5;
    int p0 = pp * 2;
    half4v* colh = (half4v*)(xf + (size_t)b * 2048 * 512 + p0);

    // cooperative twiddle-table fill (2 passes over 512 threads)
    for (int i = t; i < 682; i += 512) {
        int h, off;
        if (i < 512)      { h = 512; off = 0; }
        else if (i < 640) { h = 128; off = 512; }
        else if (i < 672) { h = 32;  off = 640; }
        else if (i < 680) { h = 8;   off = 672; }
        else              { h = 2;   off = 680; }
        int pos = i - off;
        float s, c;
        __sincosf(-6.28318530717958647692f * (float)pos / (float)(4 * h), &s, &c);
        twd[i] = (half2v){(_Float16)c, (_Float16)s};
    }

#pragma unroll
    for (int c = 0; c < 4; c++) {
        int s = t + 512 * c;
        half4v h = colh[(size_t)s * 256];
        buf[pidx4(s)] = make_float4((float)h.x, (float)h.y, (float)h.z, (float)h.w);
    }
    __syncthreads(); r4_fwd(buf, t, 512, twd);
    __syncthreads(); r4_fwd(buf, t, 128, twd + 512);
    __syncthreads(); r4_fwd(buf, t, 32, twd + 640);
    __syncthreads(); r4_fwd(buf, t, 8, twd + 672);
    __syncthreads(); r4_fwd(buf, t, 2, twd + 680);
    __syncthreads();
#pragma unroll
    for (int c = 0; c < 2; c++) {
        int pr = t + 512 * c;
        int ia = pidx4(2 * pr), ib = pidx4(2 * pr + 1);
        float4 a = buf[ia], bb = buf[ib];
        buf[ia] = make_float4(a.x + bb.x, a.y + bb.y, a.z + bb.z, a.w + bb.w);
        buf[ib] = make_float4(a.x - bb.x, a.y - bb.y, a.z - bb.z, a.w - bb.w);
    }
    __syncthreads();

    int f0 = __brev((unsigned)p0) >> 23;
    int f1 = __brev((unsigned)(p0 + 1)) >> 23;
    float qw0r = qr[f0], qw0i = qi[f0], kw0r = kr[f0], kw0i = ki[f0], vw0r = vr[f0], vw0i = vi[f0];
    float qw1r = qr[f1], qw1i = qi[f1], kw1r = kr[f1], kw1i = ki[f1], vw1r = vr[f1], vw1i = vi[f1];
#pragma unroll
    for (int c = 0; c < 4; c++) {
        int idx = pidx4(t + 512 * c);
        float4 y = buf[idx];
        {
            float yr = y.x, yi = y.y;
            float qre = yr * qw0r - yi * qw0i, qim = yr * qw0i + yi * qw0r;
            float kre = yr * kw0r - yi * kw0i + 1e-12f, kim = yr * kw0i + yi * kw0r;
            float vre = yr * vw0r - yi * vw0i, vim = yr * vw0i + yi * vw0r;
            float inv = 1.0f / (kre * kre + kim * kim);
            float dre = (qre * kre + qim * kim) * inv;
            float dim = (qim * kre - qre * kim) * inv;
            y.x = dre * vre - dim * vim;
            y.y = dre * vim + dim * vre;
        }
        {
            float yr = y.z, yi = y.w;
            float qre = yr * qw1r - yi * qw1i, qim = yr * qw1i + yi * qw1r;
            float kre = yr * kw1r - yi * kw1i + 1e-12f, kim = yr * kw1i + yi * kw1r;
            float vre = yr * vw1r - yi * vw1i, vim = yr * vw1i + yi * vw1r;
            float inv = 1.0f / (kre * kre + kim * kim);
            float dre = (qre * kre + qim * kim) * inv;
            float dim = (qim * kre - qre * kim) * inv;
            y.z = dre * vre - dim * vim;
            y.w = dre * vim + dim * vre;
        }
        buf[idx] = y;
    }

    __syncthreads();
#pragma unroll
    for (int c = 0; c < 2; c++) {
        int pr = t + 512 * c;
        int ia = pidx4(2 * pr), ib = pidx4(2 * pr + 1);
        float4 a = buf[ia], bb = buf[ib];
        buf[ia] = make_float4(a.x + bb.x, a.y + bb.y, a.z + bb.z, a.w + bb.w);
        buf[ib] = make_float4(a.x - bb.x, a.y - bb.y, a.z - bb.z, a.w - bb.w);
    }
    __syncthreads(); r4_inv(buf, t, 2, twd + 680);
    __syncthreads(); r4_inv(buf, t, 8, twd + 672);
    __syncthreads(); r4_inv(buf, t, 32, twd + 640);
    __syncthreads(); r4_inv(buf, t, 128, twd + 512);
    __syncthreads(); r4_inv(buf, t, 512, twd);
    __syncthreads();

    const float sc = 1.0f / 2048.0f;
    float r0r = rtr[f0] * sc, r0i = rti[f0] * sc;
    float r1r = rtr[f1] * sc, r1i = rti[f1] * sc;
#pragma unroll
    for (int c = 0; c < 4; c++) {
        int s = t + 512 * c;
        float4 z = buf[pidx4(s)];
        float ox = z.x * r0r - z.y * r0i, oy = z.x * r0i + z.y * r0r;
        float oz = z.z * r1r - z.w * r1i, ow = z.z * r1i + z.w * r1r;
        colh[(size_t)s * 256] = (half4v){(_Float16)ox, (_Float16)oy, (_Float16)oz, (_Float16)ow};
    }
}

// ---------------- k3 : row-pair residual + dyt_b + q/k (Parseval-packed) + v ----------------
__global__ __launch_bounds__(256, 4) void k3_mid(
        const half2v* __restrict__ xf,
        const float* __restrict__ x,
        const float* __restrict__ alpha, const float* __restrict__ w, const float* __restrict__ bia,
        const float* __restrict__ qr, const float* __restrict__ qi,
        const float* __restrict__ kr, const float* __restrict__ ki,
        const float* __restrict__ vr, const float* __restrict__ vi,
        float* __restrict__ x1,
        unsigned short* __restrict__ qb, unsigned short* __restrict__ kb, unsigned short* __restrict__ vb) {
    __shared__ __align__(16) char smem[4 * 1024 * 8];  // 32KB
    int tid = threadIdx.x, lane = tid & 63, wv = tid >> 6;
    float2* zb = (float2*)(smem + wv * 8192);          // phase1: wave-private 8KB
    float* wbs = (float*)smem;                          // [6][512]=12KB (after combine)
    float2* zf = (float2*)(smem + 12288 + wv * 4096);  // phase2: wave-private 4KB
    size_t pr = (size_t)blockIdx.x * 4 + wv;
    size_t r1 = pr * 2, r2 = r1 + 1;
    float tc[12], ts[12];
    wtw512(tc, ts, lane);

    float xa[8], xb2[8];
#pragma unroll
    for (int j = 0; j < 8; j++) {
        int d = j * 64 + lane;
        half2v h1 = xf[r1 * 512 + d];
        half2v h2 = xf[r2 * 512 + d];
        zb[d]       = make_float2((float)h1.x, (float)h1.y);
        zb[512 + d] = make_float2((float)h2.x, (float)h2.y);
        xa[j]  = x[r1 * 512 + d];
        xb2[j] = x[r2 * 512 + d];
    }
    float re[8], im[8];
#pragma unroll
    for (int j = 0; j < 8; j++) {
        int d = j * 64 + lane;
        int fd = __brev((unsigned)d) >> 23;
        int dp = __brev((unsigned)((512 - fd) & 511)) >> 23;
        float2 z1 = zb[d], z1p = zb[dp];
        float2 z2 = zb[512 + d], z2p = zb[512 + dp];
        float h1r = 0.5f * (z1.x + z1p.x), h1i = 0.5f * (z1.y - z1p.y);
        float h2r = 0.5f * (z2.x + z2p.x), h2i = 0.5f * (z2.y - z2p.y);
        re[j] = h1r - h2i;
        im[j] = h1i + h2r;
    }
    __syncthreads();
    for (int idx = tid; idx < 512; idx += 256) {
        int f = __brev((unsigned)idx) >> 23;
        int gg = (512 - f) & 511;
        float aa = (f == 0 || f == 256) ? 0.04419417382415922f : 0.0625f;
        float ah = aa * 0.5f;
        const float s5 = 0.5f * (1.0f / 512.0f);
        wbs[0 * 512 + idx] = ah * (qr[f] + qr[gg]); wbs[1 * 512 + idx] = ah * (qi[f] - qi[gg]);
        wbs[2 * 512 + idx] = ah * (kr[f] + kr[gg]); wbs[3 * 512 + idx] = ah * (ki[f] - ki[gg]);
        wbs[4 * 512 + idx] = s5 * (vr[f] + vr[gg]); wbs[5 * 512 + idx] = s5 * (vi[f] - vi[gg]);
    }

    wfft512<true>(re, im, tc, ts, lane);
    float a = alpha[0];
    float gre[8], gim[8];
#pragma unroll
    for (int j = 0; j < 8; j++) {
        int d = j * 64 + lane;
        float v1 = re[j] * (1.0f / 512.0f) + xa[j];
        float v2 = im[j] * (1.0f / 512.0f) + xb2[j];
        x1[r1 * 512 + d] = v1;
        x1[r2 * 512 + d] = v2;
        gre[j] = dyt_tanh(a * v1) * w[d] + bia[d];
        gim[j] = dyt_tanh(a * v2) * w[d] + bia[d];
    }
    wfft512<false>(gre, gim, tc, ts, lane);
    __syncthreads();

#pragma unroll
    for (int j = 0; j < 8; j++)
        zf[j * 64 + lane] = make_float2(gre[j], gim[j]);

    float pvr[8], pvi[8];
#pragma unroll
    for (int j = 0; j < 8; j++) {
        int i = j * 64 + lane;
        float wr0 = wbs[4 * 512 + i], wi0 = wbs[5 * 512 + i];
        pvr[j] = gre[j] * wr0 - gim[j] * wi0;
        pvi[j] = gre[j] * wi0 + gim[j] * wr0;
    }

    bool odd = (lane & 1) != 0;
#pragma unroll
    for (int j = 0; j < 8; j++) {
        int d = j * 64 + lane;
        int fd = __brev((unsigned)d) >> 23;
        int dp = __brev((unsigned)((512 - fd) & 511)) >> 23;
        float2 Zp = zf[dp];
        float zr = gre[j], zi = gim[j];
        float A1r = 0.5f * (zr + Zp.x), A1i = 0.5f * (zi - Zp.y);
        float A2r = 0.5f * (zi + Zp.y), A2i = 0.5f * (Zp.x - zr);
        float wr0 = wbs[0 * 512 + d], wi0 = wbs[1 * 512 + d];
        float Q1r = A1r * wr0 - A1i * wi0, Q1i = A1r * wi0 + A1i * wr0;
        float Q2r = A2r * wr0 - A2i * wi0, Q2i = A2r * wi0 + A2i * wr0;
        qb[r1 * 512 + d] = f2bf(odd ? -Q1i : Q1r);
        qb[r2 * 512 + d] = f2bf(odd ? -Q2i : Q2r);
        float wr1 = wbs[2 * 512 + d], wi1 = wbs[3 * 512 + d];
        float K1r = A1r * wr1 - A1i * wi1, K1i = A1r * wi1 + A1i * wr1;
        float K2r = A2r * wr1 - A2i * wi1, K2i = A2r * wi1 + A2i * wr1;
        kb[r1 * 512 + d] = f2bf(odd ? -K1i : K1r);
        kb[r2 * 512 + d] = f2bf(odd ? -K2i : K2r);
    }

    wfft512<true>(pvr, pvi, tc, ts, lane);
#pragma unroll
    for (int j = 0; j < 8; j++) {
        int d = j * 64 + lane;
        vb[r1 * 512 + d] = f2bf(pvr[j]);
        vb[r2 * 512 + d] = f2bf(pvi[j]);
    }
}

// ---------------- unified bt-GEMM (BK=64, global_load_lds, XOR-swizzled LDS) ----------------
__global__ __launch_bounds__(256) void gemm_bt(
        const unsigned short* __restrict__ A, const unsigned short* __restrict__ Bt,
        void* __restrict__ C, int M, int N, int Ks, int kseg, float scale, int out_half) {
    int tilesM = M >> 7, tilesN = N >> 7;
    int perBatch = tilesM * tilesN;
    int l = blockIdx.x;
    int seg = blockIdx.y;
    int s = l & 7, t = l >> 3;
    int cnt = perBatch >> 3;
    int bz = t / cnt;
    int u = t - bz * cnt;
    int pn = tilesN >> 1, pm = tilesM >> 2;
    int n0 = ((s & 1) * pn + (u % pn)) << 7;
    int m0 = ((s >> 1) * pm + (u / pn)) << 7;
    int kbase = seg * kseg;

    const unsigned short* Ab = A + (size_t)bz * M * Ks;
    const unsigned short* Bb = Bt + (size_t)bz * N * Ks;
    __shared__ __align__(16) unsigned short smem[2 * 128 * 64];
    unsigned short* As = smem;
    unsigned short* Bs = smem + 128 * 64;
    int tid = threadIdx.x;
    int wave = tid >> 6, lane = tid & 63;
    int wm = (wave >> 1) * 64, wn = (wave & 1) * 64;
    int lrow = lane & 15, lq = lane >> 4;
    floatx4 acc[4][4];
#pragma unroll
    for (int i = 0; i < 4; i++)
#pragma unroll
        for (int j = 0; j < 4; j++)
            acc[i][j] = (floatx4){0.f, 0.f, 0.f, 0.f};

    int lr = lane >> 3;
    int lcs = lane & 7;
    for (int k0 = kbase; k0 < kbase + kseg; k0 += 64) {
        __syncthreads();
#pragma unroll
        for (int i = 0; i < 4; i++) {
            int c = wave * 4 + i;
            int r = c * 8 + lr;
            int gcol = ((lcs ^ (r & 7)) << 3);
            async_load16(Ab + (size_t)(m0 + r) * Ks + k0 + gcol, As + c * 512);
            async_load16(Bb + (size_t)(n0 + r) * Ks + k0 + gcol, Bs + c * 512);
        }
        __syncthreads();
        bf16x8 a0[4], a1[4], b0[4], b1[4];
#pragma unroll
        for (int mi = 0; mi < 4; mi++) {
            int r = wm + mi * 16 + lrow;
            a0[mi] = *(const bf16x8*)(As + r * 64 + ((lq ^ (r & 7)) << 3));
            a1[mi] = *(const bf16x8*)(As + r * 64 + (((lq + 4) ^ (r & 7)) << 3));
        }
#pragma unroll
        for (int ni = 0; ni < 4; ni++) {
            int r = wn + ni * 16 + lrow;
            b0[ni] = *(const bf16x8*)(Bs + r * 64 + ((lq ^ (r & 7)) << 3));
            b1[ni] = *(const bf16x8*)(Bs + r * 64 + (((lq + 4) ^ (r & 7)) << 3));
        }
#pragma unroll
        for (int mi = 0; mi < 4; mi++)
#pragma unroll
            for (int ni = 0; ni < 4; ni++) {
                acc[mi][ni] = __builtin_amdgcn_mfma_f32_16x16x32_bf16(a0[mi], b0[ni], acc[mi][ni], 0, 0, 0);
                acc[mi][ni] = __builtin_amdgcn_mfma_f32_16x16x32_bf16(a1[mi], b1[ni], acc[mi][ni], 0, 0, 0);
            }
    }
    size_t cbase = ((size_t)seg * 4 + bz) * (size_t)M * N;
    int lr0 = (wave >> 1) * 16 + lq * 4;
    for (int mi = 0; mi < 4; mi++) {
        __syncthreads();
        if (out_half) {
            _Float16* Cs = (_Float16*)smem;
            for (int ni = 0; ni < 4; ni++)
                for (int r = 0; r < 4; r++)
                    Cs[(lr0 + r) * 128 + wn + ni * 16 + lrow] = (_Float16)(acc[mi][ni][r] * scale);
            __syncthreads();
            for (int h = 0; h < 2; h++) {
                int chunk = tid + h * 256;
                int rl = chunk >> 4, cb = (chunk & 15) * 16;
                int grow = m0 + mi * 16 + (rl & 15) + (rl >> 4) * 64;
                *(uint4*)((char*)C + (cbase + (size_t)grow * N + n0) * 2 + cb) =
                    *(const uint4*)((const char*)Cs + rl * 256 + cb);
            }
        } else {
            float* Cs = (float*)smem;
            for (int ni = 0; ni < 4; ni++)
                for (int r = 0; r < 4; r++)
                    Cs[(lr0 + r) * 128 + wn + ni * 16 + lrow] = acc[mi][ni][r] * scale;
            __syncthreads();
            for (int h = 0; h < 4; h++) {
                int chunk = tid + h * 256;
                int rl = chunk >> 5, cb = (chunk & 31) * 16;
                int grow = m0 + mi * 16 + (rl & 15) + (rl >> 4) * 64;
                *(uint4*)((char*)C + (cbase + (size_t)grow * N + n0) * 4 + cb) =
                    *(const uint4*)((const char*)Cs + rl * 512 + cb);
            }
        }
    }
}

// ---------------- softmax (in-place bf16 P) + v->vT transpose, one grid ----------------
__global__ __launch_bounds__(256) void sm_tr(
        const _Float16* __restrict__ Sc, unsigned short* __restrict__ P,
        const unsigned short* __restrict__ vb, unsigned short* __restrict__ vT) {
    __shared__ __align__(16) char lds[64 * 65 * 2];  // transpose tile; softmax uses first 16B
    if (blockIdx.x < 8192) {
        float* red = (float*)lds;
        int tid = threadIdx.x;
        size_t row = blockIdx.x;
        halfx8 hv = *(const halfx8*)(Sc + row * 2048 + tid * 8);
        float v[8];
#pragma unroll
        for (int j = 0; j < 8; j++) v[j] = (float)hv[j];
        float mx = v[0];
#pragma unroll
        for (int j = 1; j < 8; j++) mx = fmaxf(mx, v[j]);
        for (int off = 32; off >= 1; off >>= 1) mx = fmaxf(mx, __shfl_xor(mx, off));
        int wv = tid >> 6;
        if ((tid & 63) == 0) red[wv] = mx;
        __syncthreads();
        mx = fmaxf(fmaxf(red[0], red[1]), fmaxf(red[2], red[3]));
        float e[8], sum = 0.f;
#pragma unroll
        for (int j = 0; j < 8; j++) { e[j] = __expf(v[j] - mx); sum += e[j]; }
        for (int off = 32; off >= 1; off >>= 1) sum += __shfl_xor(sum, off);
        __syncthreads();
        if ((tid & 63) == 0) red[wv] = sum;
        __syncthreads();
        float inv = 1.0f / (red[0] + red[1] + red[2] + red[3]);
        ushortx8 o;
#pragma unroll
        for (int j = 0; j < 8; j++) o[j] = f2bf(e[j] * inv);
        *(ushortx8*)(P + row * 2048 + tid * 8) = o;
    } else {
        unsigned short (*tile)[65] = (unsigned short (*)[65])lds;
        int id = blockIdx.x - 8192;           // 1024 transpose blocks: (32, 8, 4)
        int sx = id & 31, dy = (id >> 5) & 7, bz = id >> 8;
        int s0 = sx * 64, d0 = dy * 64;
        int tx = threadIdx.x & 63, ty = threadIdx.x >> 6;
        for (int j = 0; j < 16; j++) {
            int s = ty + j * 4;
            tile[s][tx] = vb[((size_t)bz * 2048 + s0 + s) * 512 + d0 + tx];
        }
        __syncthreads();
        for (int j = 0; j < 16; j++) {
            int d = ty + j * 4;
            vT[((size_t)bz * 512 + d0 + d) * 2048 + s0 + tx] = tile[tx][d];
        }
    }
}

// ---------------- k5 : row-pair residual + dyt_f + spectral filter ----------------
// Sums TWO fp16 split-K partials.
__global__ __launch_bounds__(256, 4) void k5_ffn(
        const _Float16* __restrict__ attn0, const _Float16* __restrict__ attn1,
        const float* __restrict__ x1,
        const float* __restrict__ alpha, const float* __restrict__ w, const float* __restrict__ bia,
        const float* __restrict__ br, const float* __restrict__ bi,
        float* __restrict__ out) {
    __shared__ float wbs[2][512];
    int tid = threadIdx.x, lane = tid & 63, wv = tid >> 6;
    size_t pr = (size_t)blockIdx.x * 4 + wv;
    size_t r1 = pr * 2, r2 = r1 + 1;
    for (int idx = tid; idx < 512; idx += 256) {
        int f = __brev((unsigned)idx) >> 23;
        int gg = (512 - f) & 511;
        wbs[0][idx] = 0.5f * (br[f] + br[gg]) * (1.0f / 512.0f);
        wbs[1][idx] = 0.5f * (bi[f] - bi[gg]) * (1.0f / 512.0f);
    }
    float tc[12], ts[12];
    wtw512(tc, ts, lane);
    float a = alpha[0];
    float re[8], im[8], x2a[8], x2b[8];
#pragma unroll
    for (int j = 0; j < 8; j++) {
        int d = j * 64 + lane;
        float v1 = (float)attn0[r1 * 512 + d] + (float)attn1[r1 * 512 + d] + x1[r1 * 512 + d];
        float v2 = (float)attn0[r2 * 512 + d] + (float)attn1[r2 * 512 + d] + x1[r2 * 512 + d];
        x2a[j] = v1; x2b[j] = v2;
        re[j] = dyt_tanh(a * v1) * w[d] + bia[d];
        im[j] = dyt_tanh(a * v2) * w[d] + bia[d];
    }
    wfft512<false>(re, im, tc, ts, lane);
    __syncthreads();
#pragma unroll
    for (int j = 0; j < 8; j++) {
        int i = j * 64 + lane;
        float wr0 = wbs[0][i], wi0 = wbs[1][i];
        float rr = re[j], ii = im[j];
        re[j] = rr * wr0 - ii * wi0;
        im[j] = rr * wi0 + ii * wr0;
    }
    wfft512<true>(re, im, tc, ts, lane);
#pragma unroll
    for (int j = 0; j < 8; j++) {
        int d = j * 64 + lane;
        out[r1 * 512 + d] = re[j] + x2a[j];
        out[r2 * 512 + d] = im[j] + x2b[j];
    }
}

extern "C" void kernel_launch(void* const* d_in, const int* in_sizes, int n_in,
                              void* d_out, int out_size, void* d_ws, size_t ws_size,
                              hipStream_t stream) {
    const float* x      = (const float*)d_in[0];
    const float* a_qr   = (const float*)d_in[1];
    const float* a_kr   = (const float*)d_in[2];
    const float* a_vr   = (const float*)d_in[3];
    const float* a_rtr  = (const float*)d_in[4];
    const float* b_qr   = (const float*)d_in[5];
    const float* b_kr   = (const float*)d_in[6];
    const float* b_vr   = (const float*)d_in[7];
    /* f_ar = d_in[8] unused (dead gelu branch) */
    const float* f_br   = (const float*)d_in[9];
    const float* a_qi   = (const float*)d_in[10];
    const float* a_ki   = (const float*)d_in[11];
    const float* a_vi   = (const float*)d_in[12];
    const float* a_rti  = (const float*)d_in[13];
    const float* b_qi   = (const float*)d_in[14];
    const float* b_ki   = (const float*)d_in[15];
    const float* b_vi   = (const float*)d_in[16];
    /* f_ai = d_in[17] unused */
    const float* f_bi   = (const float*)d_in[18];
    /* f_bias = d_in[19] unused (dead gelu branch) */
    const float* dyta_alpha = (const float*)d_in[20];
    const float* dyta_w     = (const float*)d_in[21];
    const float* dyta_b     = (const float*)d_in[22];
    const float* dytb_alpha = (const float*)d_in[23];
    const float* dytb_w     = (const float*)d_in[24];
    const float* dytb_b     = (const float*)d_in[25];
    const float* dytf_alpha = (const float*)d_in[26];
    const float* dytf_w     = (const float*)d_in[27];
    const float* dytf_b     = (const float*)d_in[28];
    (void)in_sizes; (void)n_in; (void)out_size; (void)ws_size;

    char* ws = (char*)d_ws;
    const size_t MB = 1024 * 1024;
    half2v* xfH = (half2v*)(ws + 0 * MB);           // 16MB packed fp16 complex
    float* x1   = (float*)(ws + 32 * MB);           // 16MB
    unsigned short* qb = (unsigned short*)(ws + 48 * MB);  // 8MB
    unsigned short* kb = (unsigned short*)(ws + 56 * MB);  // 8MB
    unsigned short* vb = (unsigned short*)(ws + 64 * MB);  // 8MB
    unsigned short* vT = (unsigned short*)(ws + 72 * MB);  // 8MB
    _Float16* scores   = (_Float16*)(ws + 0 * MB);  // 32MB, overlays dead xfH
    unsigned short* Pb = (unsigned short*)(ws + 0 * MB);   // bf16 P, in place over scores
    _Float16* attnP    = (_Float16*)(ws + 81 * MB); // 16MB: two 8MB fp16 K-split partials
    float* outp = (float*)d_out;

    k1_dyt_fftd<<<2048, 256, 0, stream>>>(x, dyta_alpha, dyta_w, dyta_b, xfH);
    k2_sfft<<<1024, 512, 0, stream>>>(xfH, a_qr, a_qi, a_kr, a_ki, a_vr, a_vi, a_rtr, a_rti);
    k3_mid<<<1024, 256, 0, stream>>>(xfH, x, dytb_alpha, dytb_w, dytb_b,
                                     b_qr, b_qi, b_kr, b_ki, b_vr, b_vi, x1, qb, kb, vb);
    gemm_bt<<<1024, 256, 0, stream>>>(qb, kb, scores, 2048, 2048, 512, 512,
                                      0.04419417382415922f, 1);
    sm_tr<<<9216, 256, 0, stream>>>(scores, Pb, vb, vT);
    gemm_bt<<<dim3(256, 2), 256, 0, stream>>>(Pb, vT, attnP, 2048, 512, 2048, 1024,
                                              1.0f, 1);
    k5_ffn<<<1024, 256, 0, stream>>>(attnP, attnP + (size_t)4 * 2048 * 512, x1,
                                     dytf_alpha, dytf_w, dytf_b, f_br, f_bi, outp);
}